// Round 1
// baseline (353.189 us; speedup 1.0000x reference)
//
#include <hip/hip_runtime.h>
#include <stdint.h>

typedef unsigned short u16;
typedef __attribute__((ext_vector_type(8))) short s16x8;   // bf16x8 MFMA frag (4 VGPRs)
typedef __attribute__((ext_vector_type(4))) float f32x4;   // MFMA C/D frag
typedef __attribute__((ext_vector_type(4))) unsigned short u16x4;

// ---------------- helpers ----------------

__device__ __forceinline__ u16 f2bf(float f) {
  unsigned u = __float_as_uint(f);
  unsigned r = (u + 0x7fffu + ((u >> 16) & 1u)) >> 16;   // RNE
  return (u16)r;
}

typedef const __attribute__((address_space(1))) unsigned int* gas_ptr;
typedef __attribute__((address_space(3))) unsigned int* las_ptr;

__device__ __forceinline__ void g2l16(const void* g, void* l) {
  // async global->LDS, 16B per lane; LDS dst = wave-uniform base + lane*16
  __builtin_amdgcn_global_load_lds((gas_ptr)g, (las_ptr)l, 16, 0, 0);
}

// ---------------- elementwise kernels ----------------

__global__ void f2b_kernel(const float* __restrict__ in, u16* __restrict__ out, int n) {
  const int i = (blockIdx.x * 256 + threadIdx.x) * 4;
  if (i < n) {
    const f32x4 v = *(const f32x4*)(in + i);
    u16x4 o;
    o[0] = f2bf(v[0]); o[1] = f2bf(v[1]); o[2] = f2bf(v[2]); o[3] = f2bf(v[3]);
    *(u16x4*)(out + i) = o;
  }
}

__global__ void trig_kernel(float* __restrict__ cosT, float* __restrict__ sinT) {
  const int idx = blockIdx.x * 256 + threadIdx.x;   // S*32 = 65536
  const int s = idx >> 5, j = idx & 31;
  // inv_freq = 10000^(-j/32), computed accurately then rounded to fp32
  const double invd = exp(-(double)j * 0.2878231366242558);  // ln(10000)/32
  const float a = (float)s * (float)invd;
  cosT[idx] = cosf(a);
  sinT[idx] = sinf(a);
}

// q: [B*S, 1024] f32 -> qb: [B][16][S][64] bf16, rotated, *0.125 (score scale folded in)
__global__ void rope_q_kernel(const float* __restrict__ q, u16* __restrict__ o,
                              const float* __restrict__ cosT, const float* __restrict__ sinT) {
  const int idx = blockIdx.x * 256 + threadIdx.x;   // 2^21
  const int j = idx & 31;
  const int h = (idx >> 5) & 15;
  const int s = (idx >> 9) & 2047;
  const int b = idx >> 20;
  const long row = (long)b * 2048 + s;
  const float x1 = q[row * 1024 + h * 64 + j];
  const float x2 = q[row * 1024 + h * 64 + 32 + j];
  const float c = cosT[s * 32 + j], sn = sinT[s * 32 + j];
  const long ob = (((long)(b * 16 + h)) * 2048 + s) * 64;
  o[ob + j]      = f2bf((x1 * c - x2 * sn) * 0.125f);
  o[ob + 32 + j] = f2bf((x2 * c + x1 * sn) * 0.125f);
}

// k: [B*S, 256] f32 -> kb: [B][4][S][64] bf16, rotated
__global__ void rope_k_kernel(const float* __restrict__ k, u16* __restrict__ o,
                              const float* __restrict__ cosT, const float* __restrict__ sinT) {
  const int idx = blockIdx.x * 256 + threadIdx.x;   // 2^19
  const int j = idx & 31;
  const int kv = (idx >> 5) & 3;
  const int s = (idx >> 7) & 2047;
  const int b = idx >> 18;
  const long row = (long)b * 2048 + s;
  const float x1 = k[row * 256 + kv * 64 + j];
  const float x2 = k[row * 256 + kv * 64 + 32 + j];
  const float c = cosT[s * 32 + j], sn = sinT[s * 32 + j];
  const long ob = (((long)(b * 4 + kv)) * 2048 + s) * 64;
  o[ob + j]      = f2bf(x1 * c - x2 * sn);
  o[ob + 32 + j] = f2bf(x2 * c + x1 * sn);
}

// v: [B*S, 256] f32 -> vb: [B][4][S][64] bf16
__global__ void conv_v_kernel(const float* __restrict__ v, u16* __restrict__ o) {
  const int idx = blockIdx.x * 256 + threadIdx.x;   // 2^20
  const int d = idx & 63;
  const int kv = (idx >> 6) & 3;
  const int s = (idx >> 8) & 2047;
  const int b = idx >> 19;
  const long row = (long)b * 2048 + s;
  o[(((long)(b * 4 + kv)) * 2048 + s) * 64 + d] = f2bf(v[row * 256 + kv * 64 + d]);
}

// ---------------- GEMM: Y[M,N] = A[M,K](bf16) @ W[N,K](bf16)^T ----------------
// 128x128 tile, BK=32, 4 waves in 2x2, each wave 4x4 16x16 frags.

__global__ __launch_bounds__(256, 2) void gemm_bt_kernel(
    const u16* __restrict__ A, const u16* __restrict__ W,
    float* __restrict__ Yf, u16* __restrict__ Yb,
    int M, int N, int K) {
  __shared__ __align__(16) u16 As[128 * 32];
  __shared__ __align__(16) u16 Bs[128 * 32];
  const int tid = threadIdx.x;
  const int lane = tid & 63;
  const int wave = tid >> 6;
  const int wr = wave >> 1, wc = wave & 1;
  const long arow0 = (long)blockIdx.x * 128;
  const long wrow0 = (long)blockIdx.y * 128;
  const u16* Ab = A + arow0 * K;
  const u16* Wb = W + wrow0 * K;

  f32x4 acc[4][4] = {};

  for (int k0 = 0; k0 < K; k0 += 32) {
    __syncthreads();
#pragma unroll
    for (int i = 0; i < 2; ++i) {
      const int c = wave * 128 + i * 64 + lane;        // 0..511 chunk id
      const int r = c >> 2, c16 = c & 3;               // row, 16B-col within 64B row
      g2l16(Ab + (long)r * K + k0 + c16 * 8, (char*)As + (wave * 128 + i * 64) * 16);
      g2l16(Wb + (long)r * K + k0 + c16 * 8, (char*)Bs + (wave * 128 + i * 64) * 16);
    }
    __syncthreads();
    s16x8 af[4], bfr[4];
#pragma unroll
    for (int m = 0; m < 4; ++m) {
      const int row = wr * 64 + m * 16 + (lane & 15);
      af[m] = *(const s16x8*)&As[row * 32 + (lane >> 4) * 8];
    }
#pragma unroll
    for (int n = 0; n < 4; ++n) {
      const int row = wc * 64 + n * 16 + (lane & 15);
      bfr[n] = *(const s16x8*)&Bs[row * 32 + (lane >> 4) * 8];
    }
#pragma unroll
    for (int m = 0; m < 4; ++m)
#pragma unroll
      for (int n = 0; n < 4; ++n)
        acc[m][n] = __builtin_amdgcn_mfma_f32_16x16x32_bf16(af[m], bfr[n], acc[m][n], 0, 0, 0);
  }

#pragma unroll
  for (int m = 0; m < 4; ++m)
#pragma unroll
    for (int n = 0; n < 4; ++n) {
      const long gr0 = arow0 + wr * 64 + m * 16 + (lane >> 4) * 4;
      const long gc = wrow0 + wc * 64 + n * 16 + (lane & 15);
#pragma unroll
      for (int r = 0; r < 4; ++r) {
        const long off = (gr0 + r) * N + gc;
        if (Yf) Yf[off] = acc[m][n][r];
        else    Yb[off] = f2bf(acc[m][n][r]);
      }
    }
}

// ---------------- flash attention ----------------
// grid (qt=32, h=16, b=2), 256 thr = 4 waves, wave w owns q rows [qt*64+w*16, +16)
// K/V/P tiles in LDS with 16B-granule XOR swizzle (2-way conflicts only).

__global__ __launch_bounds__(256, 2) void flash_kernel(
    const u16* __restrict__ qg,   // [B][16][S][64]
    const u16* __restrict__ kg,   // [B][4][S][64]
    const u16* __restrict__ vg,   // [B][4][S][64]
    u16* __restrict__ og) {       // [B][S][1024]
  const int qt = blockIdx.x, h = blockIdx.y, b = blockIdx.z;
  const int kvh = h >> 2;
  const int tid = threadIdx.x, lane = tid & 63, w = tid >> 6;

  __shared__ __align__(16) u16 Kl[64 * 64];
  __shared__ __align__(16) u16 Vt[64 * 64];      // transposed: [d][kv]
  __shared__ __align__(16) u16 Pl[4][16 * 64];   // per-wave P

  const u16* Qp = qg + (((long)(b * 16 + h)) * 2048 + qt * 64 + w * 16) * 64;
  s16x8 qf[2];
  {
    const int r16 = lane & 15, ko = (lane >> 4) * 8;
    qf[0] = *(const s16x8*)(Qp + r16 * 64 + ko);
    qf[1] = *(const s16x8*)(Qp + r16 * 64 + 32 + ko);
  }

  const u16* Kp = kg + ((long)(b * 4 + kvh)) * 2048 * 64;
  const u16* Vp = vg + ((long)(b * 4 + kvh)) * 2048 * 64;

  f32x4 of[4] = {};
  float mrow[4], lrow[4];
#pragma unroll
  for (int r = 0; r < 4; ++r) { mrow[r] = -1e30f; lrow[r] = 0.f; }

  const int qrow0 = qt * 64 + w * 16 + (lane >> 4) * 4;

  for (int kt = 0; kt <= qt; ++kt) {
    __syncthreads();   // protect LDS from previous iteration's readers
#pragma unroll
    for (int i = 0; i < 2; ++i) {
      const int c = tid + i * 256;               // 0..511
      const int row = c >> 3, c8 = c & 7;
      const s16x8 kvl = *(const s16x8*)(Kp + ((long)(kt * 64 + row)) * 64 + c8 * 8);
      *(s16x8*)((char*)Kl + row * 128 + ((c8 ^ (row & 7)) << 4)) = kvl;
      const s16x8 vvl = *(const s16x8*)(Vp + ((long)(kt * 64 + row)) * 64 + c8 * 8);
#pragma unroll
      for (int j = 0; j < 8; ++j) {
        const int d = c8 * 8 + j;
        const int colb = row * 2;                 // byte col (kv index) in Vt row
        *(u16*)((char*)Vt + d * 128 + ((((colb >> 4) ^ (d & 7)) << 4) | (colb & 15))) = (u16)vvl[j];
      }
    }
    __syncthreads();

    // S = Q @ K^T   (scale pre-folded into Q)
    f32x4 sf[4] = {};
#pragma unroll
    for (int ks = 0; ks < 2; ++ks)
#pragma unroll
      for (int fn = 0; fn < 4; ++fn) {
        const int row = fn * 16 + (lane & 15);
        const int gk = ks * 4 + (lane >> 4);
        const s16x8 kf = *(const s16x8*)((char*)Kl + row * 128 + ((gk ^ (row & 7)) << 4));
        sf[fn] = __builtin_amdgcn_mfma_f32_16x16x32_bf16(qf[ks], kf, sf[fn], 0, 0, 0);
      }

    // online softmax over this kv tile
    const bool diag = (kt == qt);
    float p4[4][4], mx[4];
#pragma unroll
    for (int r = 0; r < 4; ++r) mx[r] = -1e30f;
#pragma unroll
    for (int fn = 0; fn < 4; ++fn) {
      const int kvc = kt * 64 + fn * 16 + (lane & 15);
#pragma unroll
      for (int r = 0; r < 4; ++r) {
        float sv = sf[fn][r];
        if (diag && (kvc > qrow0 + r)) sv = -1e30f;
        p4[fn][r] = sv;
        mx[r] = fmaxf(mx[r], sv);
      }
    }
#pragma unroll
    for (int off = 1; off < 16; off <<= 1)
#pragma unroll
      for (int r = 0; r < 4; ++r)
        mx[r] = fmaxf(mx[r], __shfl_xor(mx[r], off));

    float alpha[4], rs[4];
#pragma unroll
    for (int r = 0; r < 4; ++r) {
      const float mn = fmaxf(mrow[r], mx[r]);
      alpha[r] = __expf(mrow[r] - mn);
      mrow[r] = mn;
      rs[r] = 0.f;
    }
#pragma unroll
    for (int fn = 0; fn < 4; ++fn)
#pragma unroll
      for (int r = 0; r < 4; ++r) {
        const float pe = __expf(p4[fn][r] - mrow[r]);
        p4[fn][r] = pe;
        rs[r] += pe;
      }
#pragma unroll
    for (int off = 1; off < 16; off <<= 1)
#pragma unroll
      for (int r = 0; r < 4; ++r)
        rs[r] += __shfl_xor(rs[r], off);
#pragma unroll
    for (int r = 0; r < 4; ++r) lrow[r] = lrow[r] * alpha[r] + rs[r];
#pragma unroll
    for (int fd = 0; fd < 4; ++fd)
#pragma unroll
      for (int r = 0; r < 4; ++r) of[fd][r] *= alpha[r];

    // P -> LDS (bf16, swizzled), then O += P @ V
    u16* Pw = Pl[w];
#pragma unroll
    for (int fn = 0; fn < 4; ++fn)
#pragma unroll
      for (int r = 0; r < 4; ++r) {
        const int row = (lane >> 4) * 4 + r;
        const int colb = (fn * 16 + (lane & 15)) * 2;
        *(u16*)((char*)Pw + row * 128 + ((((colb >> 4) ^ (row & 7)) << 4) | (colb & 15))) = f2bf(p4[fn][r]);
      }
#pragma unroll
    for (int ks = 0; ks < 2; ++ks) {
      const int prow = lane & 15;
      const int pgk = ks * 4 + (lane >> 4);
      const s16x8 pa = *(const s16x8*)((char*)Pw + prow * 128 + ((pgk ^ (prow & 7)) << 4));
#pragma unroll
      for (int fd = 0; fd < 4; ++fd) {
        const int vrow = fd * 16 + (lane & 15);
        const s16x8 vf = *(const s16x8*)((char*)Vt + vrow * 128 + ((pgk ^ (vrow & 7)) << 4));
        of[fd] = __builtin_amdgcn_mfma_f32_16x16x32_bf16(pa, vf, of[fd], 0, 0, 0);
      }
    }
  }

  // normalize + store to [B][S][h*64+d]
  const long orow0 = (long)b * 2048 + qt * 64 + w * 16 + (lane >> 4) * 4;
#pragma unroll
  for (int r = 0; r < 4; ++r) {
    const float inv = 1.0f / lrow[r];
    const long gb = (orow0 + r) * 1024 + h * 64;
#pragma unroll
    for (int fd = 0; fd < 4; ++fd)
      og[gb + fd * 16 + (lane & 15)] = f2bf(of[fd][r] * inv);
  }
}

// ---------------- launch ----------------

extern "C" void kernel_launch(void* const* d_in, const int* in_sizes, int n_in,
                              void* d_out, int out_size, void* d_ws, size_t ws_size,
                              hipStream_t stream) {
  (void)in_sizes; (void)n_in; (void)out_size; (void)ws_size;
  const float* x  = (const float*)d_in[0];
  const float* wq = (const float*)d_in[1];
  const float* wk = (const float*)d_in[2];
  const float* wv = (const float*)d_in[3];
  const float* wo = (const float*)d_in[4];
  float* out = (float*)d_out;

  char* p = (char*)d_ws;
  auto alloc = [&](size_t bytes) { char* r = p; p += (bytes + 255) & ~(size_t)255; return r; };

  u16* xb    = (u16*)alloc(4096ull * 1024 * 2);
  u16* wqb   = (u16*)alloc(1024ull * 1024 * 2);
  u16* wkb   = (u16*)alloc(256ull * 1024 * 2);
  u16* wvb   = (u16*)alloc(256ull * 1024 * 2);
  u16* wob   = (u16*)alloc(1024ull * 1024 * 2);
  float* qpre = (float*)alloc(4096ull * 1024 * 4);
  float* kpre = (float*)alloc(4096ull * 256 * 4);
  float* vpre = (float*)alloc(4096ull * 256 * 4);
  u16* qrb   = (u16*)alloc(4096ull * 1024 * 2);
  u16* krb   = (u16*)alloc(4096ull * 256 * 2);
  u16* vrb   = (u16*)alloc(4096ull * 256 * 2);
  u16* aob   = (u16*)alloc(4096ull * 1024 * 2);
  float* cosT = (float*)alloc(2048ull * 32 * 4);
  float* sinT = (float*)alloc(2048ull * 32 * 4);

  // bf16 conversions
  f2b_kernel<<<4096, 256, 0, stream>>>(x, xb, 4194304);
  f2b_kernel<<<1024, 256, 0, stream>>>(wq, wqb, 1048576);
  f2b_kernel<<<256, 256, 0, stream>>>(wk, wkb, 262144);
  f2b_kernel<<<256, 256, 0, stream>>>(wv, wvb, 262144);
  f2b_kernel<<<1024, 256, 0, stream>>>(wo, wob, 1048576);
  trig_kernel<<<256, 256, 0, stream>>>(cosT, sinT);

  // projections
  gemm_bt_kernel<<<dim3(32, 8), 256, 0, stream>>>(xb, wqb, qpre, nullptr, 4096, 1024, 1024);
  gemm_bt_kernel<<<dim3(32, 2), 256, 0, stream>>>(xb, wkb, kpre, nullptr, 4096, 256, 1024);
  gemm_bt_kernel<<<dim3(32, 2), 256, 0, stream>>>(xb, wvb, vpre, nullptr, 4096, 256, 1024);

  // rope + layout to [B][heads][S][D] bf16
  rope_q_kernel<<<8192, 256, 0, stream>>>(qpre, qrb, cosT, sinT);
  rope_k_kernel<<<2048, 256, 0, stream>>>(kpre, krb, cosT, sinT);
  conv_v_kernel<<<4096, 256, 0, stream>>>(vpre, vrb);

  // causal GQA flash attention
  flash_kernel<<<dim3(32, 16, 2), 256, 0, stream>>>(qrb, krb, vrb, aob);

  // output projection (fp32 out)
  gemm_bt_kernel<<<dim3(32, 8), 256, 0, stream>>>(aob, wob, out, nullptr, 4096, 1024, 1024);
}

// Round 2
// 204.230 us; speedup vs baseline: 1.7294x; 1.7294x over previous
//
#include <hip/hip_runtime.h>
#include <stdint.h>

typedef unsigned short u16;
typedef __attribute__((ext_vector_type(8))) short s16x8;   // bf16x8 MFMA frag (4 VGPRs)
typedef __attribute__((ext_vector_type(4))) float f32x4;   // MFMA C/D frag
typedef __attribute__((ext_vector_type(4))) unsigned short u16x4;

// ---------------- helpers ----------------

__device__ __forceinline__ u16 f2bf(float f) {
  unsigned u = __float_as_uint(f);
  unsigned r = (u + 0x7fffu + ((u >> 16) & 1u)) >> 16;   // RNE
  return (u16)r;
}

typedef const __attribute__((address_space(1))) unsigned int* gas_ptr;
typedef __attribute__((address_space(3))) unsigned int* las_ptr;

__device__ __forceinline__ void g2l16(const void* g, void* l) {
  // async global->LDS, 16B per lane; LDS dst = wave-uniform base + lane*16
  __builtin_amdgcn_global_load_lds((gas_ptr)g, (las_ptr)l, 16, 0, 0);
}

// ---------------- elementwise kernels ----------------

__global__ void f2b_kernel(const float* __restrict__ in, u16* __restrict__ out, int n) {
  const int i = (blockIdx.x * 256 + threadIdx.x) * 4;
  if (i < n) {
    const f32x4 v = *(const f32x4*)(in + i);
    u16x4 o;
    o[0] = f2bf(v[0]); o[1] = f2bf(v[1]); o[2] = f2bf(v[2]); o[3] = f2bf(v[3]);
    *(u16x4*)(out + i) = o;
  }
}

__global__ void trig_kernel(float* __restrict__ cosT, float* __restrict__ sinT) {
  const int idx = blockIdx.x * 256 + threadIdx.x;   // S*32 = 65536
  const int s = idx >> 5, j = idx & 31;
  const double invd = exp(-(double)j * 0.2878231366242558);  // ln(10000)/32
  const float a = (float)s * (float)invd;
  cosT[idx] = cosf(a);
  sinT[idx] = sinf(a);
}

// ---------------- fused QKV projection GEMM ----------------
// Y[4096,1536] = X[4096,1024](bf16) @ Wcat[1536,1024]^T, epilogue applies
// RoPE (+0.125 scale for Q) and writes:
//   Q  -> [B][16][S][64] bf16    (cols 0..1023)
//   K  -> [B][4][S][64]  bf16    (cols 1024..1279, rope)
//   V^T-> [B][4][64][S]  bf16    (cols 1280..1535, transposed)

__global__ __launch_bounds__(256, 2) void gemm_qkv_kernel(
    const u16* __restrict__ A, const u16* __restrict__ W,
    u16* __restrict__ qo, u16* __restrict__ ko, u16* __restrict__ vto,
    const float* __restrict__ cosT, const float* __restrict__ sinT) {
  const int K = 1024;
  __shared__ __align__(16) u16 As[128 * 32];
  __shared__ __align__(16) u16 Bs[128 * 32];
  const int tid = threadIdx.x;
  const int lane = tid & 63;
  const int wave = tid >> 6;
  const int wr = wave >> 1, wc = wave & 1;
  const long arow0 = (long)blockIdx.x * 128;
  const long wrow0 = (long)blockIdx.y * 128;
  const u16* Ab = A + arow0 * K;
  const u16* Wb = W + wrow0 * K;

  f32x4 acc[4][4] = {};

  for (int k0 = 0; k0 < K; k0 += 32) {
    __syncthreads();
#pragma unroll
    for (int i = 0; i < 2; ++i) {
      const int c = wave * 128 + i * 64 + lane;
      const int r = c >> 2, c16 = c & 3;
      g2l16(Ab + (long)r * K + k0 + c16 * 8, (char*)As + (wave * 128 + i * 64) * 16);
      g2l16(Wb + (long)r * K + k0 + c16 * 8, (char*)Bs + (wave * 128 + i * 64) * 16);
    }
    __syncthreads();
    s16x8 af[4], bfr[4];
#pragma unroll
    for (int m = 0; m < 4; ++m) {
      const int row = wr * 64 + m * 16 + (lane & 15);
      af[m] = *(const s16x8*)&As[row * 32 + (lane >> 4) * 8];
    }
#pragma unroll
    for (int n = 0; n < 4; ++n) {
      const int row = wc * 64 + n * 16 + (lane & 15);
      bfr[n] = *(const s16x8*)&Bs[row * 32 + (lane >> 4) * 8];
    }
    __builtin_amdgcn_s_setprio(1);
#pragma unroll
    for (int m = 0; m < 4; ++m)
#pragma unroll
      for (int n = 0; n < 4; ++n)
        acc[m][n] = __builtin_amdgcn_mfma_f32_16x16x32_bf16(af[m], bfr[n], acc[m][n], 0, 0, 0);
    __builtin_amdgcn_s_setprio(0);
  }

  const int colBase = (int)wrow0 + wc * 64;   // head-aligned, wave-uniform
  const int j0 = lane & 15;

  if (colBase < 1024) {                       // ---- Q: rope + 0.125 scale ----
    const int h2 = colBase >> 6;
#pragma unroll
    for (int m = 0; m < 4; ++m) {
      const int grow = (int)arow0 + wr * 64 + m * 16 + (lane >> 4) * 4;
#pragma unroll
      for (int r = 0; r < 4; ++r) {
        const int row = grow + r;
        const int s = row & 2047, bb = row >> 11;
        const long ob = (((long)(bb * 16 + h2)) * 2048 + s) * 64;
        const float c0 = cosT[s * 32 + j0],      s0 = sinT[s * 32 + j0];
        const float c1 = cosT[s * 32 + 16 + j0], s1 = sinT[s * 32 + 16 + j0];
        qo[ob + j0]      = f2bf((acc[m][0][r] * c0 - acc[m][2][r] * s0) * 0.125f);
        qo[ob + 16 + j0] = f2bf((acc[m][1][r] * c1 - acc[m][3][r] * s1) * 0.125f);
        qo[ob + 32 + j0] = f2bf((acc[m][2][r] * c0 + acc[m][0][r] * s0) * 0.125f);
        qo[ob + 48 + j0] = f2bf((acc[m][3][r] * c1 + acc[m][1][r] * s1) * 0.125f);
      }
    }
  } else if (colBase < 1280) {                // ---- K: rope ----
    const int kvh2 = (colBase - 1024) >> 6;
#pragma unroll
    for (int m = 0; m < 4; ++m) {
      const int grow = (int)arow0 + wr * 64 + m * 16 + (lane >> 4) * 4;
#pragma unroll
      for (int r = 0; r < 4; ++r) {
        const int row = grow + r;
        const int s = row & 2047, bb = row >> 11;
        const long ob = (((long)(bb * 4 + kvh2)) * 2048 + s) * 64;
        const float c0 = cosT[s * 32 + j0],      s0 = sinT[s * 32 + j0];
        const float c1 = cosT[s * 32 + 16 + j0], s1 = sinT[s * 32 + 16 + j0];
        ko[ob + j0]      = f2bf(acc[m][0][r] * c0 - acc[m][2][r] * s0);
        ko[ob + 16 + j0] = f2bf(acc[m][1][r] * c1 - acc[m][3][r] * s1);
        ko[ob + 32 + j0] = f2bf(acc[m][2][r] * c0 + acc[m][0][r] * s0);
        ko[ob + 48 + j0] = f2bf(acc[m][3][r] * c1 + acc[m][1][r] * s1);
      }
    }
  } else {                                    // ---- V: write transposed ----
    const int kvh2 = (colBase - 1280) >> 6;
#pragma unroll
    for (int m = 0; m < 4; ++m) {
      const int grow = (int)arow0 + wr * 64 + m * 16 + (lane >> 4) * 4;
#pragma unroll
      for (int r = 0; r < 4; ++r) {
        const int row = grow + r;
        const int s = row & 2047, bb = row >> 11;
#pragma unroll
        for (int n = 0; n < 4; ++n) {
          const int d = n * 16 + j0;
          vto[(((long)(bb * 4 + kvh2)) * 64 + d) * 2048 + s] = f2bf(acc[m][n][r]);
        }
      }
    }
  }
}

// ---------------- output projection GEMM (fp32 out) ----------------

__global__ __launch_bounds__(256, 2) void gemm_out_kernel(
    const u16* __restrict__ A, const u16* __restrict__ W, float* __restrict__ Y) {
  const int K = 1024, N = 1024;
  __shared__ __align__(16) u16 As[128 * 32];
  __shared__ __align__(16) u16 Bs[128 * 32];
  const int tid = threadIdx.x;
  const int lane = tid & 63;
  const int wave = tid >> 6;
  const int wr = wave >> 1, wc = wave & 1;
  const long arow0 = (long)blockIdx.x * 128;
  const long wrow0 = (long)blockIdx.y * 128;
  const u16* Ab = A + arow0 * K;
  const u16* Wb = W + wrow0 * K;

  f32x4 acc[4][4] = {};

  for (int k0 = 0; k0 < K; k0 += 32) {
    __syncthreads();
#pragma unroll
    for (int i = 0; i < 2; ++i) {
      const int c = wave * 128 + i * 64 + lane;
      const int r = c >> 2, c16 = c & 3;
      g2l16(Ab + (long)r * K + k0 + c16 * 8, (char*)As + (wave * 128 + i * 64) * 16);
      g2l16(Wb + (long)r * K + k0 + c16 * 8, (char*)Bs + (wave * 128 + i * 64) * 16);
    }
    __syncthreads();
    s16x8 af[4], bfr[4];
#pragma unroll
    for (int m = 0; m < 4; ++m) {
      const int row = wr * 64 + m * 16 + (lane & 15);
      af[m] = *(const s16x8*)&As[row * 32 + (lane >> 4) * 8];
    }
#pragma unroll
    for (int n = 0; n < 4; ++n) {
      const int row = wc * 64 + n * 16 + (lane & 15);
      bfr[n] = *(const s16x8*)&Bs[row * 32 + (lane >> 4) * 8];
    }
    __builtin_amdgcn_s_setprio(1);
#pragma unroll
    for (int m = 0; m < 4; ++m)
#pragma unroll
      for (int n = 0; n < 4; ++n)
        acc[m][n] = __builtin_amdgcn_mfma_f32_16x16x32_bf16(af[m], bfr[n], acc[m][n], 0, 0, 0);
    __builtin_amdgcn_s_setprio(0);
  }

#pragma unroll
  for (int m = 0; m < 4; ++m)
#pragma unroll
    for (int n = 0; n < 4; ++n) {
      const long gr0 = arow0 + wr * 64 + m * 16 + (lane >> 4) * 4;
      const long gc = wrow0 + wc * 64 + n * 16 + (lane & 15);
#pragma unroll
      for (int r = 0; r < 4; ++r)
        Y[(gr0 + r) * N + gc] = acc[m][n][r];
    }
}

// ---------------- flash attention ----------------
// grid (16 pairs, 16 h, 2 b), 256 thr = 4 waves; each block processes q-tiles
// i and 31-i sequentially (33 kv-tiles total -> balanced).
// K and V^T staged via global_load_lds with inverse-swizzled source; reads
// use the same XOR involution (rule #21).

__global__ __launch_bounds__(256, 2) void flash_kernel(
    const u16* __restrict__ qg,   // [B][16][S][64]
    const u16* __restrict__ kg,   // [B][4][S][64]
    const u16* __restrict__ vtg,  // [B][4][64][S]  (V transposed)
    u16* __restrict__ og) {       // [B][S][1024]
  const int pr = blockIdx.x, h = blockIdx.y, b = blockIdx.z;
  const int kvh = h >> 2;
  const int tid = threadIdx.x, lane = tid & 63, w = tid >> 6;

  __shared__ __align__(16) u16 Kl[64 * 64];   // [kv][d], XOR-swizzled 16B chunks
  __shared__ __align__(16) u16 Vl[64 * 64];   // [d][kv], XOR-swizzled 16B chunks
  __shared__ __align__(16) u16 Pl[4][16 * 64];

  const u16* Kp = kg  + ((long)(b * 4 + kvh)) * 2048 * 64;
  const u16* Vp = vtg + ((long)(b * 4 + kvh)) * 64 * 2048;

#pragma unroll 1
  for (int pass = 0; pass < 2; ++pass) {
    const int qt = pass ? (31 - pr) : pr;
    const u16* Qp = qg + (((long)(b * 16 + h)) * 2048 + qt * 64 + w * 16) * 64;
    s16x8 qf[2];
    {
      const int r16 = lane & 15, ko2 = (lane >> 4) * 8;
      qf[0] = *(const s16x8*)(Qp + r16 * 64 + ko2);
      qf[1] = *(const s16x8*)(Qp + r16 * 64 + 32 + ko2);
    }
    f32x4 of[4] = {};
    float mrow[4], lrow[4];
#pragma unroll
    for (int r = 0; r < 4; ++r) { mrow[r] = -1e30f; lrow[r] = 0.f; }
    const int qrow0 = qt * 64 + w * 16 + (lane >> 4) * 4;

#pragma unroll 1
    for (int kt = 0; kt <= qt; ++kt) {
      __syncthreads();   // previous tile's readers done
#pragma unroll
      for (int j = 0; j < 2; ++j) {
        const int lbase = j * 256 + w * 64;          // wave-uniform chunk base
        const int c = lbase + lane;
        const int row = c >> 3, c8 = c & 7;
        const int cs = (c8 ^ (row & 7)) * 8;         // inverse-swizzled source
        g2l16(Kp + ((long)(kt * 64 + row)) * 64 + cs, (char*)Kl + lbase * 16);
        g2l16(Vp + (long)row * 2048 + kt * 64 + cs,  (char*)Vl + lbase * 16);
      }
      __syncthreads();

      // S = Q @ K^T (scale pre-folded into Q)
      f32x4 sf[4] = {};
      __builtin_amdgcn_s_setprio(1);
#pragma unroll
      for (int ks = 0; ks < 2; ++ks)
#pragma unroll
        for (int fn = 0; fn < 4; ++fn) {
          const int row = fn * 16 + (lane & 15);
          const int gk = ks * 4 + (lane >> 4);
          const s16x8 kf = *(const s16x8*)((char*)Kl + row * 128 + ((gk ^ (row & 7)) << 4));
          sf[fn] = __builtin_amdgcn_mfma_f32_16x16x32_bf16(qf[ks], kf, sf[fn], 0, 0, 0);
        }
      __builtin_amdgcn_s_setprio(0);

      // online softmax
      const bool diag = (kt == qt);
      float p4[4][4], mx[4];
#pragma unroll
      for (int r = 0; r < 4; ++r) mx[r] = -1e30f;
#pragma unroll
      for (int fn = 0; fn < 4; ++fn) {
        const int kvc = kt * 64 + fn * 16 + (lane & 15);
#pragma unroll
        for (int r = 0; r < 4; ++r) {
          float sv = sf[fn][r];
          if (diag && (kvc > qrow0 + r)) sv = -1e30f;
          p4[fn][r] = sv;
          mx[r] = fmaxf(mx[r], sv);
        }
      }
#pragma unroll
      for (int off = 1; off < 16; off <<= 1)
#pragma unroll
        for (int r = 0; r < 4; ++r)
          mx[r] = fmaxf(mx[r], __shfl_xor(mx[r], off));

      float alpha[4], rs[4];
#pragma unroll
      for (int r = 0; r < 4; ++r) {
        const float mn = fmaxf(mrow[r], mx[r]);
        alpha[r] = __expf(mrow[r] - mn);
        mrow[r] = mn;
        rs[r] = 0.f;
      }
#pragma unroll
      for (int fn = 0; fn < 4; ++fn)
#pragma unroll
        for (int r = 0; r < 4; ++r) {
          const float pe = __expf(p4[fn][r] - mrow[r]);
          p4[fn][r] = pe;
          rs[r] += pe;
        }
#pragma unroll
      for (int off = 1; off < 16; off <<= 1)
#pragma unroll
        for (int r = 0; r < 4; ++r)
          rs[r] += __shfl_xor(rs[r], off);
#pragma unroll
      for (int r = 0; r < 4; ++r) lrow[r] = lrow[r] * alpha[r] + rs[r];
#pragma unroll
      for (int fd = 0; fd < 4; ++fd)
#pragma unroll
        for (int r = 0; r < 4; ++r) of[fd][r] *= alpha[r];

      // P -> LDS (bf16, swizzled), then O += P @ V
      u16* Pw = Pl[w];
#pragma unroll
      for (int fn = 0; fn < 4; ++fn)
#pragma unroll
        for (int r = 0; r < 4; ++r) {
          const int row = (lane >> 4) * 4 + r;
          const int colb = (fn * 16 + (lane & 15)) * 2;
          *(u16*)((char*)Pw + row * 128 + ((((colb >> 4) ^ (row & 7)) << 4) | (colb & 15))) = f2bf(p4[fn][r]);
        }
      __builtin_amdgcn_s_setprio(1);
#pragma unroll
      for (int ks = 0; ks < 2; ++ks) {
        const int prow = lane & 15;
        const int pgk = ks * 4 + (lane >> 4);
        const s16x8 pa = *(const s16x8*)((char*)Pw + prow * 128 + ((pgk ^ (prow & 7)) << 4));
#pragma unroll
        for (int fd = 0; fd < 4; ++fd) {
          const int vrow = fd * 16 + (lane & 15);
          const s16x8 vf = *(const s16x8*)((char*)Vl + vrow * 128 + ((pgk ^ (vrow & 7)) << 4));
          of[fd] = __builtin_amdgcn_mfma_f32_16x16x32_bf16(pa, vf, of[fd], 0, 0, 0);
        }
      }
      __builtin_amdgcn_s_setprio(0);
    }

    // normalize + store to [B][S][h*64+d]
    const long orow0 = (long)b * 2048 + qt * 64 + w * 16 + (lane >> 4) * 4;
#pragma unroll
    for (int r = 0; r < 4; ++r) {
      const float inv = 1.0f / lrow[r];
      const long gb = (orow0 + r) * 1024 + h * 64;
#pragma unroll
      for (int fd = 0; fd < 4; ++fd)
        og[gb + fd * 16 + (lane & 15)] = f2bf(of[fd][r] * inv);
    }
  }
}

// ---------------- launch ----------------

extern "C" void kernel_launch(void* const* d_in, const int* in_sizes, int n_in,
                              void* d_out, int out_size, void* d_ws, size_t ws_size,
                              hipStream_t stream) {
  (void)in_sizes; (void)n_in; (void)out_size; (void)ws_size;
  const float* x  = (const float*)d_in[0];
  const float* wq = (const float*)d_in[1];
  const float* wk = (const float*)d_in[2];
  const float* wv = (const float*)d_in[3];
  const float* wo = (const float*)d_in[4];
  float* out = (float*)d_out;

  char* p = (char*)d_ws;
  auto alloc = [&](size_t bytes) { char* r = p; p += (bytes + 255) & ~(size_t)255; return r; };

  u16* xb    = (u16*)alloc(4096ull * 1024 * 2);
  u16* wcat  = (u16*)alloc(1536ull * 1024 * 2);   // [wq; wk; wv]
  u16* wob   = (u16*)alloc(1024ull * 1024 * 2);
  u16* qrb   = (u16*)alloc(4096ull * 1024 * 2);   // [B][16][S][64]
  u16* krb   = (u16*)alloc(4096ull * 256 * 2);    // [B][4][S][64]
  u16* vtb   = (u16*)alloc(4096ull * 256 * 2);    // [B][4][64][S]
  u16* aob   = (u16*)alloc(4096ull * 1024 * 2);   // [B][S][1024]
  float* cosT = (float*)alloc(2048ull * 32 * 4);
  float* sinT = (float*)alloc(2048ull * 32 * 4);

  // bf16 conversions (weights into concat layout)
  f2b_kernel<<<4096, 256, 0, stream>>>(x, xb, 4194304);
  f2b_kernel<<<1024, 256, 0, stream>>>(wq, wcat, 1048576);
  f2b_kernel<<<256, 256, 0, stream>>>(wk, wcat + 1024 * 1024, 262144);
  f2b_kernel<<<256, 256, 0, stream>>>(wv, wcat + 1280 * 1024, 262144);
  f2b_kernel<<<1024, 256, 0, stream>>>(wo, wob, 1048576);
  trig_kernel<<<256, 256, 0, stream>>>(cosT, sinT);

  // fused QKV projection + rope + layout
  gemm_qkv_kernel<<<dim3(32, 12), 256, 0, stream>>>(xb, wcat, qrb, krb, vtb, cosT, sinT);

  // causal GQA flash attention (balanced pairs)
  flash_kernel<<<dim3(16, 16, 2), 256, 0, stream>>>(qrb, krb, vtb, aob);

  // output projection (fp32 out)
  gemm_out_kernel<<<dim3(32, 8), 256, 0, stream>>>(aob, wob, out);
}

// Round 4
// 176.943 us; speedup vs baseline: 1.9961x; 1.1542x over previous
//
#include <hip/hip_runtime.h>
#include <stdint.h>

typedef unsigned short u16;
typedef __attribute__((ext_vector_type(8))) short s16x8;   // bf16x8 MFMA frag (4 VGPRs)
typedef __attribute__((ext_vector_type(4))) float f32x4;   // MFMA C/D frag
typedef __attribute__((ext_vector_type(4))) unsigned short u16x4;

// ---------------- helpers ----------------

__device__ __forceinline__ u16 f2bf(float f) {
  unsigned u = __float_as_uint(f);
  unsigned r = (u + 0x7fffu + ((u >> 16) & 1u)) >> 16;   // RNE
  return (u16)r;
}
__device__ __forceinline__ unsigned pack2(float a, float b) {
  return (unsigned)f2bf(a) | ((unsigned)f2bf(b) << 16);
}
__device__ __forceinline__ float exp2fast(float x) {
  return __builtin_amdgcn_exp2f(x);   // v_exp_f32: D = 2^S0
}

typedef const __attribute__((address_space(1))) unsigned int* gas_ptr;
typedef __attribute__((address_space(3))) unsigned int* las_ptr;

__device__ __forceinline__ void g2l16(const void* g, void* l) {
  __builtin_amdgcn_global_load_lds((gas_ptr)g, (las_ptr)l, 16, 0, 0);
}

__device__ __forceinline__ void cvt4(const float* __restrict__ in, u16* __restrict__ out) {
  const f32x4 v = *(const f32x4*)in;
  u16x4 o;
  o[0] = f2bf(v[0]); o[1] = f2bf(v[1]); o[2] = f2bf(v[2]); o[3] = f2bf(v[3]);
  *(u16x4*)out = o;
}

// ---------------- fused prep: all bf16 conversions + trig tables ----------------

__global__ void prep_kernel(const float* __restrict__ x,  const float* __restrict__ wq,
                            const float* __restrict__ wk, const float* __restrict__ wv,
                            const float* __restrict__ wo,
                            u16* __restrict__ xb, u16* __restrict__ wcat, u16* __restrict__ wob,
                            float* __restrict__ cosT, float* __restrict__ sinT) {
  const long id = (long)blockIdx.x * 256 + threadIdx.x;
  if (id < 262144) {                       // wq -> wcat rows 0..1023
    cvt4(wq + id * 4, wcat + id * 4);
  } else if (id < 327680) {                // wk -> wcat rows 1024..1279
    const long i = id - 262144;
    cvt4(wk + i * 4, wcat + 1048576 + i * 4);
  } else if (id < 393216) {                // wv -> wcat rows 1280..1535
    const long i = id - 327680;
    cvt4(wv + i * 4, wcat + 1310720 + i * 4);
  } else if (id < 655360) {                // wo
    const long i = id - 393216;
    cvt4(wo + i * 4, wob + i * 4);
  } else if (id < 671744) {                // trig tables, 4 entries per id
    const long t = id - 655360;
#pragma unroll
    for (int u = 0; u < 4; ++u) {
      const long idx = t * 4 + u;
      const int s = (int)(idx >> 5), j = (int)(idx & 31);
      const double invd = exp(-(double)j * 0.2878231366242558);  // ln(10000)/32
      const float a = (float)s * (float)invd;
      cosT[idx] = cosf(a);
      sinT[idx] = sinf(a);
    }
  } else {                                 // x
    const long i = id - 671744;
    cvt4(x + i * 4, xb + i * 4);
  }
}

// ---------------- fused QKV projection GEMM ----------------
// Y[4096,1536] = X @ Wcat^T; epilogue: RoPE, Q scaled by 0.125*log2(e), writes
//   Q  -> [B][16][S][64] bf16, K -> [B][4][S][64] bf16, V^T -> [B][4][64][S] bf16

__global__ __launch_bounds__(256, 2) void gemm_qkv_kernel(
    const u16* __restrict__ A, const u16* __restrict__ W,
    u16* __restrict__ qo, u16* __restrict__ ko, u16* __restrict__ vto,
    const float* __restrict__ cosT, const float* __restrict__ sinT) {
  const int K = 1024;
  __shared__ __align__(16) u16 As[128 * 32];
  __shared__ __align__(16) u16 Bs[128 * 32];
  const int tid = threadIdx.x;
  const int lane = tid & 63;
  const int wave = tid >> 6;
  const int wr = wave >> 1, wc = wave & 1;
  const long arow0 = (long)blockIdx.x * 128;
  const long wrow0 = (long)blockIdx.y * 128;
  const u16* Ab = A + arow0 * K;
  const u16* Wb = W + wrow0 * K;

  f32x4 acc[4][4] = {};

  for (int k0 = 0; k0 < K; k0 += 32) {
    __syncthreads();
#pragma unroll
    for (int i = 0; i < 2; ++i) {
      const int c = wave * 128 + i * 64 + lane;
      const int r = c >> 2, c16 = c & 3;
      g2l16(Ab + (long)r * K + k0 + c16 * 8, (char*)As + (wave * 128 + i * 64) * 16);
      g2l16(Wb + (long)r * K + k0 + c16 * 8, (char*)Bs + (wave * 128 + i * 64) * 16);
    }
    __syncthreads();
    s16x8 af[4], bfr[4];
#pragma unroll
    for (int m = 0; m < 4; ++m) {
      const int row = wr * 64 + m * 16 + (lane & 15);
      af[m] = *(const s16x8*)&As[row * 32 + (lane >> 4) * 8];
    }
#pragma unroll
    for (int n = 0; n < 4; ++n) {
      const int row = wc * 64 + n * 16 + (lane & 15);
      bfr[n] = *(const s16x8*)&Bs[row * 32 + (lane >> 4) * 8];
    }
    __builtin_amdgcn_s_setprio(1);
#pragma unroll
    for (int m = 0; m < 4; ++m)
#pragma unroll
      for (int n = 0; n < 4; ++n)
        acc[m][n] = __builtin_amdgcn_mfma_f32_16x16x32_bf16(af[m], bfr[n], acc[m][n], 0, 0, 0);
    __builtin_amdgcn_s_setprio(0);
  }

  const int colBase = (int)wrow0 + wc * 64;
  const int j0 = lane & 15;
  const float QSCALE = 0.18033688011112042f;   // 0.125 * log2(e): softmax done in base 2

  if (colBase < 1024) {                       // ---- Q: rope + scale ----
    const int h2 = colBase >> 6;
#pragma unroll
    for (int m = 0; m < 4; ++m) {
      const int grow = (int)arow0 + wr * 64 + m * 16 + (lane >> 4) * 4;
#pragma unroll
      for (int r = 0; r < 4; ++r) {
        const int row = grow + r;
        const int s = row & 2047, bb = row >> 11;
        const long ob = (((long)(bb * 16 + h2)) * 2048 + s) * 64;
        const float c0 = cosT[s * 32 + j0],      s0 = sinT[s * 32 + j0];
        const float c1 = cosT[s * 32 + 16 + j0], s1 = sinT[s * 32 + 16 + j0];
        qo[ob + j0]      = f2bf((acc[m][0][r] * c0 - acc[m][2][r] * s0) * QSCALE);
        qo[ob + 16 + j0] = f2bf((acc[m][1][r] * c1 - acc[m][3][r] * s1) * QSCALE);
        qo[ob + 32 + j0] = f2bf((acc[m][2][r] * c0 + acc[m][0][r] * s0) * QSCALE);
        qo[ob + 48 + j0] = f2bf((acc[m][3][r] * c1 + acc[m][1][r] * s1) * QSCALE);
      }
    }
  } else if (colBase < 1280) {                // ---- K: rope ----
    const int kvh2 = (colBase - 1024) >> 6;
#pragma unroll
    for (int m = 0; m < 4; ++m) {
      const int grow = (int)arow0 + wr * 64 + m * 16 + (lane >> 4) * 4;
#pragma unroll
      for (int r = 0; r < 4; ++r) {
        const int row = grow + r;
        const int s = row & 2047, bb = row >> 11;
        const long ob = (((long)(bb * 4 + kvh2)) * 2048 + s) * 64;
        const float c0 = cosT[s * 32 + j0],      s0 = sinT[s * 32 + j0];
        const float c1 = cosT[s * 32 + 16 + j0], s1 = sinT[s * 32 + 16 + j0];
        ko[ob + j0]      = f2bf(acc[m][0][r] * c0 - acc[m][2][r] * s0);
        ko[ob + 16 + j0] = f2bf(acc[m][1][r] * c1 - acc[m][3][r] * s1);
        ko[ob + 32 + j0] = f2bf(acc[m][2][r] * c0 + acc[m][0][r] * s0);
        ko[ob + 48 + j0] = f2bf(acc[m][3][r] * c1 + acc[m][1][r] * s1);
      }
    }
  } else {                                    // ---- V: write transposed ----
    const int kvh2 = (colBase - 1280) >> 6;
#pragma unroll
    for (int m = 0; m < 4; ++m) {
      const int grow = (int)arow0 + wr * 64 + m * 16 + (lane >> 4) * 4;
#pragma unroll
      for (int r = 0; r < 4; ++r) {
        const int row = grow + r;
        const int s = row & 2047, bb = row >> 11;
#pragma unroll
        for (int n = 0; n < 4; ++n) {
          const int d = n * 16 + j0;
          vto[(((long)(bb * 4 + kvh2)) * 64 + d) * 2048 + s] = f2bf(acc[m][n][r]);
        }
      }
    }
  }
}

// ---------------- output projection GEMM (fp32 out) ----------------

__global__ __launch_bounds__(256, 2) void gemm_out_kernel(
    const u16* __restrict__ A, const u16* __restrict__ W, float* __restrict__ Y) {
  const int K = 1024, N = 1024;
  __shared__ __align__(16) u16 As[128 * 32];
  __shared__ __align__(16) u16 Bs[128 * 32];
  const int tid = threadIdx.x;
  const int lane = tid & 63;
  const int wave = tid >> 6;
  const int wr = wave >> 1, wc = wave & 1;
  const long arow0 = (long)blockIdx.x * 128;
  const long wrow0 = (long)blockIdx.y * 128;
  const u16* Ab = A + arow0 * K;
  const u16* Wb = W + wrow0 * K;

  f32x4 acc[4][4] = {};

  for (int k0 = 0; k0 < K; k0 += 32) {
    __syncthreads();
#pragma unroll
    for (int i = 0; i < 2; ++i) {
      const int c = wave * 128 + i * 64 + lane;
      const int r = c >> 2, c16 = c & 3;
      g2l16(Ab + (long)r * K + k0 + c16 * 8, (char*)As + (wave * 128 + i * 64) * 16);
      g2l16(Wb + (long)r * K + k0 + c16 * 8, (char*)Bs + (wave * 128 + i * 64) * 16);
    }
    __syncthreads();
    s16x8 af[4], bfr[4];
#pragma unroll
    for (int m = 0; m < 4; ++m) {
      const int row = wr * 64 + m * 16 + (lane & 15);
      af[m] = *(const s16x8*)&As[row * 32 + (lane >> 4) * 8];
    }
#pragma unroll
    for (int n = 0; n < 4; ++n) {
      const int row = wc * 64 + n * 16 + (lane & 15);
      bfr[n] = *(const s16x8*)&Bs[row * 32 + (lane >> 4) * 8];
    }
    __builtin_amdgcn_s_setprio(1);
#pragma unroll
    for (int m = 0; m < 4; ++m)
#pragma unroll
      for (int n = 0; n < 4; ++n)
        acc[m][n] = __builtin_amdgcn_mfma_f32_16x16x32_bf16(af[m], bfr[n], acc[m][n], 0, 0, 0);
    __builtin_amdgcn_s_setprio(0);
  }

#pragma unroll
  for (int m = 0; m < 4; ++m)
#pragma unroll
    for (int n = 0; n < 4; ++n) {
      const long gr0 = arow0 + wr * 64 + m * 16 + (lane >> 4) * 4;
      const long gc = wrow0 + wc * 64 + n * 16 + (lane & 15);
#pragma unroll
      for (int r = 0; r < 4; ++r)
        Y[(gr0 + r) * N + gc] = acc[m][n][r];
    }
}

// ---------------- flash attention (swapped QK^T, double-buffered, defer-max) ----------------
// grid 512 flat (XCD-chunked remap), 256 thr = 4 waves; block handles q-tiles pr and 31-pr.
// Per wave: 16 q rows; lane owns q = lane&15; P row fully lane-local after swapped MFMA.
// Softmax in base-2 (log2(e)*0.125 folded into Q).

__global__ __launch_bounds__(256, 2) void flash_kernel(
    const u16* __restrict__ qg,   // [B][16][S][64]
    const u16* __restrict__ kg,   // [B][4][S][64]
    const u16* __restrict__ vtg,  // [B][4][64][S]
    u16* __restrict__ og) {       // [B][S][1024]
  const int tid = threadIdx.x, lane = tid & 63, w = tid >> 6;
  const int g = lane >> 4, l15 = lane & 15;

  // XCD-chunked remap: 64 consecutive logical blocks (one kvh group) per XCD
  const int bid = blockIdx.x;
  const int lid = (bid & 7) * 64 + (bid >> 3);
  const int pr = lid & 15, h = (lid >> 4) & 15, b = lid >> 8;
  const int kvh = h >> 2;

  __shared__ __align__(16) u16 Kl[2][64 * 64];   // [kv][d], 16B-XOR swizzled
  __shared__ __align__(16) u16 Vl[2][64 * 64];   // [d][kv], 16B-XOR swizzled
  __shared__ __align__(16) u16 Pl[4][16 * 64];   // per-wave P^T [q][kv], swizzled

  const u16* Kp = kg  + ((long)(b * 4 + kvh)) * 2048 * 64;
  const u16* Vp = vtg + ((long)(b * 4 + kvh)) * 64 * 2048;

  auto STAGE = [&](int buf, int kt) {
#pragma unroll
    for (int j = 0; j < 2; ++j) {
      const int lbase = j * 256 + w * 64;          // wave-uniform chunk base
      const int c = lbase + lane;
      const int row = c >> 3, c8 = c & 7;
      const int cs = (c8 ^ (row & 7)) * 8;         // inverse-swizzled source (rule #21)
      g2l16(Kp + ((long)(kt * 64 + row)) * 64 + cs, (char*)Kl[buf] + lbase * 16);
      g2l16(Vp + (long)row * 2048 + kt * 64 + cs,  (char*)Vl[buf] + lbase * 16);
    }
  };

#pragma unroll 1
  for (int pass = 0; pass < 2; ++pass) {
    const int qt = pass ? (31 - pr) : pr;
    const u16* Qp = qg + (((long)(b * 16 + h)) * 2048 + qt * 64 + w * 16) * 64;
    const s16x8 qf0 = *(const s16x8*)(Qp + l15 * 64 + g * 8);
    const s16x8 qf1 = *(const s16x8*)(Qp + l15 * 64 + 32 + g * 8);

    f32x4 of[4] = {};
    float m = -1e30f, lsum = 0.f;
    const int qrow = qt * 64 + w * 16 + l15;

    int cur = 0;
    STAGE(0, 0);

#pragma unroll 1
    for (int kt = 0; kt <= qt; ++kt) {
      if (kt < qt) {
        STAGE(cur ^ 1, kt + 1);
        asm volatile("s_waitcnt vmcnt(4)" ::: "memory");   // cur's 4 loads done; next 4 in flight
      } else {
        asm volatile("s_waitcnt vmcnt(0)" ::: "memory");
      }
      __builtin_amdgcn_s_barrier();
      __builtin_amdgcn_sched_barrier(0);
      const u16* Kb = Kl[cur];
      const u16* Vb = Vl[cur];

      // S^T tile: mfma(K, Q) -> C[kv][q], lane owns q = l15, 16 kv values in regs
      f32x4 sf[4] = {};
      __builtin_amdgcn_s_setprio(1);
#pragma unroll
      for (int ks = 0; ks < 2; ++ks) {
        const s16x8 qv = ks ? qf1 : qf0;
#pragma unroll
        for (int fn = 0; fn < 4; ++fn) {
          const int row = fn * 16 + l15;
          const s16x8 kf = *(const s16x8*)((const char*)Kb + row * 128 + (((ks * 4 + g) ^ (row & 7)) << 4));
          sf[fn] = __builtin_amdgcn_mfma_f32_16x16x32_bf16(kf, qv, sf[fn], 0, 0, 0);
        }
      }
      __builtin_amdgcn_s_setprio(0);

      // causal mask + in-register row max (+2 shuffles across g-groups)
      const bool diag = (kt == qt);
      float p[16];
      float mx = -1e30f;
#pragma unroll
      for (int fn = 0; fn < 4; ++fn)
#pragma unroll
        for (int r = 0; r < 4; ++r) {
          float sv = sf[fn][r];
          if (diag) {
            const int kv = kt * 64 + fn * 16 + 4 * g + r;
            if (kv > qrow) sv = -1e30f;
          }
          p[fn * 4 + r] = sv;
          mx = fmaxf(mx, sv);
        }
      mx = fmaxf(mx, __shfl_xor(mx, 16));
      mx = fmaxf(mx, __shfl_xor(mx, 32));

      // defer-max (T13): rescale only when max grew by > 11 (base-2)
      if (!__all(mx - m <= 11.0f)) {
        const float mn = fmaxf(m, mx);
        const float al = exp2fast(m - mn);
        m = mn;
        lsum *= al;
        float alq[4];
#pragma unroll
        for (int r = 0; r < 4; ++r) alq[r] = __shfl(al, 4 * g + r);
#pragma unroll
        for (int fd = 0; fd < 4; ++fd)
#pragma unroll
          for (int r = 0; r < 4; ++r) of[fd][r] *= alq[r];
      }

      float rs = 0.f;
#pragma unroll
      for (int i = 0; i < 16; ++i) {
        p[i] = exp2fast(p[i] - m);
        rs += p[i];
      }
      rs += __shfl_xor(rs, 16);
      rs += __shfl_xor(rs, 32);
      lsum += rs;

      // P^T -> per-wave LDS [q][kv] as packed bf16 pairs (8 u32 writes)
#pragma unroll
      for (int fn = 0; fn < 4; ++fn) {
        const int base = fn * 32 + g * 8;            // byte col = 2*kv, kv = fn*16+4g
        char* addr = (char*)Pl[w] + l15 * 128 + ((((base >> 4) ^ (l15 & 7)) << 4) | (base & 15));
        *(unsigned*)addr       = pack2(p[fn * 4 + 0], p[fn * 4 + 1]);
        *(unsigned*)(addr + 4) = pack2(p[fn * 4 + 2], p[fn * 4 + 3]);
      }

      // O += P @ V : A-frag = P rows (q), B-frag = V^T rows (d)
      __builtin_amdgcn_s_setprio(1);
#pragma unroll
      for (int ks = 0; ks < 2; ++ks) {
        const s16x8 pa = *(const s16x8*)((const char*)Pl[w] + l15 * 128 + ((((ks * 4 + g)) ^ (l15 & 7)) << 4));
#pragma unroll
        for (int fd = 0; fd < 4; ++fd) {
          const int vrow = fd * 16 + l15;
          const s16x8 vf = *(const s16x8*)((const char*)Vb + vrow * 128 + (((ks * 4 + g) ^ (vrow & 7)) << 4));
          of[fd] = __builtin_amdgcn_mfma_f32_16x16x32_bf16(pa, vf, of[fd], 0, 0, 0);
        }
      }
      __builtin_amdgcn_s_setprio(0);

      __builtin_amdgcn_s_barrier();   // all waves done reading cur before it's restaged
      cur ^= 1;
    }

    // normalize + store; of rows are q_local = 4g+r, stats live at lane 4g+r
    float linv[4];
#pragma unroll
    for (int r = 0; r < 4; ++r) linv[r] = 1.0f / __shfl(lsum, 4 * g + r);
    const long orow0 = (long)b * 2048 + qt * 64 + w * 16 + 4 * g;
#pragma unroll
    for (int r = 0; r < 4; ++r) {
      const long gb = (orow0 + r) * 1024 + h * 64;
#pragma unroll
      for (int fd = 0; fd < 4; ++fd)
        og[gb + fd * 16 + l15] = f2bf(of[fd][r] * linv[r]);
    }
  }
}

// ---------------- launch ----------------

extern "C" void kernel_launch(void* const* d_in, const int* in_sizes, int n_in,
                              void* d_out, int out_size, void* d_ws, size_t ws_size,
                              hipStream_t stream) {
  (void)in_sizes; (void)n_in; (void)out_size; (void)ws_size;
  const float* x  = (const float*)d_in[0];
  const float* wq = (const float*)d_in[1];
  const float* wk = (const float*)d_in[2];
  const float* wv = (const float*)d_in[3];
  const float* wo = (const float*)d_in[4];
  float* out = (float*)d_out;

  char* p = (char*)d_ws;
  auto alloc = [&](size_t bytes) { char* r = p; p += (bytes + 255) & ~(size_t)255; return r; };

  u16* xb    = (u16*)alloc(4096ull * 1024 * 2);
  u16* wcat  = (u16*)alloc(1536ull * 1024 * 2);   // [wq; wk; wv]
  u16* wob   = (u16*)alloc(1024ull * 1024 * 2);
  u16* qrb   = (u16*)alloc(4096ull * 1024 * 2);   // [B][16][S][64]
  u16* krb   = (u16*)alloc(4096ull * 256 * 2);    // [B][4][S][64]
  u16* vtb   = (u16*)alloc(4096ull * 256 * 2);    // [B][4][64][S]
  u16* aob   = (u16*)alloc(4096ull * 1024 * 2);   // [B][S][1024]
  float* cosT = (float*)alloc(2048ull * 32 * 4);
  float* sinT = (float*)alloc(2048ull * 32 * 4);

  // single fused prep: weight/x conversions + trig tables
  prep_kernel<<<6720, 256, 0, stream>>>(x, wq, wk, wv, wo, xb, wcat, wob, cosT, sinT);

  // fused QKV projection + rope + layout
  gemm_qkv_kernel<<<dim3(32, 12), 256, 0, stream>>>(xb, wcat, qrb, krb, vtb, cosT, sinT);

  // causal GQA flash attention
  flash_kernel<<<512, 256, 0, stream>>>(qrb, krb, vtb, aob);

  // output projection (fp32 out)
  gemm_out_kernel<<<dim3(32, 8), 256, 0, stream>>>(aob, wob, out);
}

// Round 6
// 174.659 us; speedup vs baseline: 2.0222x; 1.0131x over previous
//
#include <hip/hip_runtime.h>
#include <stdint.h>

typedef unsigned short u16;
typedef __attribute__((ext_vector_type(8))) short s16x8;   // bf16x8 MFMA frag (4 VGPRs)
typedef __attribute__((ext_vector_type(4))) float f32x4;   // MFMA C/D frag
typedef __attribute__((ext_vector_type(4))) unsigned short u16x4;
typedef __attribute__((ext_vector_type(2))) unsigned int u32x2;

// ---------------- helpers ----------------

__device__ __forceinline__ u16 f2bf(float f) {
  unsigned u = __float_as_uint(f);
  unsigned r = (u + 0x7fffu + ((u >> 16) & 1u)) >> 16;   // RNE
  return (u16)r;
}
__device__ __forceinline__ unsigned cvt_pk(float lo, float hi) {
  unsigned r;
  asm("v_cvt_pk_bf16_f32 %0, %1, %2" : "=v"(r) : "v"(lo), "v"(hi));
  return r;
}
__device__ __forceinline__ float exp2fast(float x) {
  return __builtin_amdgcn_exp2f(x);   // v_exp_f32: D = 2^S0
}

typedef const __attribute__((address_space(1))) unsigned int* gas_ptr;
typedef __attribute__((address_space(3))) unsigned int* las_ptr;

__device__ __forceinline__ void g2l16(const void* g, void* l) {
  __builtin_amdgcn_global_load_lds((gas_ptr)g, (las_ptr)l, 16, 0, 0);
}

__device__ __forceinline__ void cvt4(const float* __restrict__ in, u16* __restrict__ out) {
  const f32x4 v = *(const f32x4*)in;
  u16x4 o;
  o[0] = f2bf(v[0]); o[1] = f2bf(v[1]); o[2] = f2bf(v[2]); o[3] = f2bf(v[3]);
  *(u16x4*)out = o;
}

// ---------------- fused prep: all bf16 conversions + trig tables ----------------

__global__ void prep_kernel(const float* __restrict__ x,  const float* __restrict__ wq,
                            const float* __restrict__ wk, const float* __restrict__ wv,
                            const float* __restrict__ wo,
                            u16* __restrict__ xb, u16* __restrict__ wcat, u16* __restrict__ wob,
                            float* __restrict__ cosT, float* __restrict__ sinT) {
  const long id = (long)blockIdx.x * 256 + threadIdx.x;
  if (id < 262144) {                       // wq -> wcat rows 0..1023
    cvt4(wq + id * 4, wcat + id * 4);
  } else if (id < 327680) {                // wk -> wcat rows 1024..1279
    const long i = id - 262144;
    cvt4(wk + i * 4, wcat + 1048576 + i * 4);
  } else if (id < 393216) {                // wv -> wcat rows 1280..1535
    const long i = id - 327680;
    cvt4(wv + i * 4, wcat + 1310720 + i * 4);
  } else if (id < 655360) {                // wo
    const long i = id - 393216;
    cvt4(wo + i * 4, wob + i * 4);
  } else if (id < 671744) {                // trig tables, 4 entries per id
    const long t = id - 655360;
#pragma unroll
    for (int u = 0; u < 4; ++u) {
      const long idx = t * 4 + u;
      const int s = (int)(idx >> 5), j = (int)(idx & 31);
      const double invd = exp(-(double)j * 0.2878231366242558);  // ln(10000)/32
      const float a = (float)s * (float)invd;
      cosT[idx] = cosf(a);
      sinT[idx] = sinf(a);
    }
  } else {                                 // x
    const long i = id - 671744;
    cvt4(x + i * 4, xb + i * 4);
  }
}

// ---------------- fused QKV projection GEMM (BK=64) ----------------
// Y[4096,1536] = X @ Wcat^T; epilogue: RoPE, Q scaled by 0.125*log2(e), writes
//   Q  -> [B][16][S][64] bf16, K -> [B][4][S][64] bf16, V^T -> [B][4][64][S] bf16

__global__ __launch_bounds__(256, 2) void gemm_qkv_kernel(
    const u16* __restrict__ A, const u16* __restrict__ W,
    u16* __restrict__ qo, u16* __restrict__ ko, u16* __restrict__ vto,
    const float* __restrict__ cosT, const float* __restrict__ sinT) {
  const int K = 1024;
  __shared__ __align__(16) u16 As[128 * 64];
  __shared__ __align__(16) u16 Bs[128 * 64];
  const int tid = threadIdx.x;
  const int lane = tid & 63;
  const int wave = tid >> 6;
  const int g = lane >> 4, l15 = lane & 15;
  const int wr = wave >> 1, wc = wave & 1;
  const long arow0 = (long)blockIdx.x * 128;
  const long wrow0 = (long)blockIdx.y * 128;
  const u16* Ab = A + arow0 * K;
  const u16* Wb = W + wrow0 * K;

  f32x4 acc[4][4] = {};

  for (int k0 = 0; k0 < K; k0 += 64) {
    __syncthreads();
#pragma unroll
    for (int i = 0; i < 4; ++i) {
      const int lbase = i * 256 + wave * 64;
      const int c = lbase + lane;
      const int r = c >> 3, c8 = c & 7;
      g2l16(Ab + (long)r * K + k0 + c8 * 8, (char*)As + lbase * 16);
      g2l16(Wb + (long)r * K + k0 + c8 * 8, (char*)Bs + lbase * 16);
    }
    __syncthreads();
#pragma unroll
    for (int ks = 0; ks < 2; ++ks) {
      s16x8 af[4], bfr[4];
#pragma unroll
      for (int m = 0; m < 4; ++m)
        af[m] = *(const s16x8*)&As[(wr * 64 + m * 16 + l15) * 64 + ks * 32 + g * 8];
#pragma unroll
      for (int n = 0; n < 4; ++n)
        bfr[n] = *(const s16x8*)&Bs[(wc * 64 + n * 16 + l15) * 64 + ks * 32 + g * 8];
      __builtin_amdgcn_s_setprio(1);
#pragma unroll
      for (int m = 0; m < 4; ++m)
#pragma unroll
        for (int n = 0; n < 4; ++n)
          acc[m][n] = __builtin_amdgcn_mfma_f32_16x16x32_bf16(af[m], bfr[n], acc[m][n], 0, 0, 0);
      __builtin_amdgcn_s_setprio(0);
    }
  }

  const int colBase = (int)wrow0 + wc * 64;
  const int j0 = l15;
  const float QSCALE = 0.18033688011112042f;   // 0.125 * log2(e): softmax done in base 2

  if (colBase < 1024) {                       // ---- Q: rope + scale ----
    const int h2 = colBase >> 6;
#pragma unroll
    for (int m = 0; m < 4; ++m) {
      const int grow = (int)arow0 + wr * 64 + m * 16 + g * 4;
#pragma unroll
      for (int r = 0; r < 4; ++r) {
        const int row = grow + r;
        const int s = row & 2047, bb = row >> 11;
        const long ob = (((long)(bb * 16 + h2)) * 2048 + s) * 64;
        const float c0 = cosT[s * 32 + j0],      s0 = sinT[s * 32 + j0];
        const float c1 = cosT[s * 32 + 16 + j0], s1 = sinT[s * 32 + 16 + j0];
        qo[ob + j0]      = f2bf((acc[m][0][r] * c0 - acc[m][2][r] * s0) * QSCALE);
        qo[ob + 16 + j0] = f2bf((acc[m][1][r] * c1 - acc[m][3][r] * s1) * QSCALE);
        qo[ob + 32 + j0] = f2bf((acc[m][2][r] * c0 + acc[m][0][r] * s0) * QSCALE);
        qo[ob + 48 + j0] = f2bf((acc[m][3][r] * c1 + acc[m][1][r] * s1) * QSCALE);
      }
    }
  } else if (colBase < 1280) {                // ---- K: rope ----
    const int kvh2 = (colBase - 1024) >> 6;
#pragma unroll
    for (int m = 0; m < 4; ++m) {
      const int grow = (int)arow0 + wr * 64 + m * 16 + g * 4;
#pragma unroll
      for (int r = 0; r < 4; ++r) {
        const int row = grow + r;
        const int s = row & 2047, bb = row >> 11;
        const long ob = (((long)(bb * 4 + kvh2)) * 2048 + s) * 64;
        const float c0 = cosT[s * 32 + j0],      s0 = sinT[s * 32 + j0];
        const float c1 = cosT[s * 32 + 16 + j0], s1 = sinT[s * 32 + 16 + j0];
        ko[ob + j0]      = f2bf(acc[m][0][r] * c0 - acc[m][2][r] * s0);
        ko[ob + 16 + j0] = f2bf(acc[m][1][r] * c1 - acc[m][3][r] * s1);
        ko[ob + 32 + j0] = f2bf(acc[m][2][r] * c0 + acc[m][0][r] * s0);
        ko[ob + 48 + j0] = f2bf(acc[m][3][r] * c1 + acc[m][1][r] * s1);
      }
    }
  } else {                                    // ---- V: write transposed ----
    const int kvh2 = (colBase - 1280) >> 6;
#pragma unroll
    for (int m = 0; m < 4; ++m) {
      const int grow = (int)arow0 + wr * 64 + m * 16 + g * 4;
#pragma unroll
      for (int r = 0; r < 4; ++r) {
        const int row = grow + r;
        const int s = row & 2047, bb = row >> 11;
#pragma unroll
        for (int n = 0; n < 4; ++n) {
          const int d = n * 16 + j0;
          vto[(((long)(bb * 4 + kvh2)) * 64 + d) * 2048 + s] = f2bf(acc[m][n][r]);
        }
      }
    }
  }
}

// ---------------- output projection GEMM (BK=64, fp32 out) ----------------

__global__ __launch_bounds__(256, 2) void gemm_out_kernel(
    const u16* __restrict__ A, const u16* __restrict__ W, float* __restrict__ Y) {
  const int K = 1024, N = 1024;
  __shared__ __align__(16) u16 As[128 * 64];
  __shared__ __align__(16) u16 Bs[128 * 64];
  const int tid = threadIdx.x;
  const int lane = tid & 63;
  const int wave = tid >> 6;
  const int g = lane >> 4, l15 = lane & 15;
  const int wr = wave >> 1, wc = wave & 1;
  const long arow0 = (long)blockIdx.x * 128;
  const long wrow0 = (long)blockIdx.y * 128;
  const u16* Ab = A + arow0 * K;
  const u16* Wb = W + wrow0 * K;

  f32x4 acc[4][4] = {};

  for (int k0 = 0; k0 < K; k0 += 64) {
    __syncthreads();
#pragma unroll
    for (int i = 0; i < 4; ++i) {
      const int lbase = i * 256 + wave * 64;
      const int c = lbase + lane;
      const int r = c >> 3, c8 = c & 7;
      g2l16(Ab + (long)r * K + k0 + c8 * 8, (char*)As + lbase * 16);
      g2l16(Wb + (long)r * K + k0 + c8 * 8, (char*)Bs + lbase * 16);
    }
    __syncthreads();
#pragma unroll
    for (int ks = 0; ks < 2; ++ks) {
      s16x8 af[4], bfr[4];
#pragma unroll
      for (int m = 0; m < 4; ++m)
        af[m] = *(const s16x8*)&As[(wr * 64 + m * 16 + l15) * 64 + ks * 32 + g * 8];
#pragma unroll
      for (int n = 0; n < 4; ++n)
        bfr[n] = *(const s16x8*)&Bs[(wc * 64 + n * 16 + l15) * 64 + ks * 32 + g * 8];
      __builtin_amdgcn_s_setprio(1);
#pragma unroll
      for (int m = 0; m < 4; ++m)
#pragma unroll
        for (int n = 0; n < 4; ++n)
          acc[m][n] = __builtin_amdgcn_mfma_f32_16x16x32_bf16(af[m], bfr[n], acc[m][n], 0, 0, 0);
      __builtin_amdgcn_s_setprio(0);
    }
  }

#pragma unroll
  for (int m = 0; m < 4; ++m)
#pragma unroll
    for (int n = 0; n < 4; ++n) {
      const long gr0 = arow0 + wr * 64 + m * 16 + g * 4;
      const long gc = wrow0 + wc * 64 + n * 16 + l15;
#pragma unroll
      for (int r = 0; r < 4; ++r)
        Y[(gr0 + r) * N + gc] = acc[m][n][r];
    }
}

// ---------------- flash attention (swapped QK^T, double-buffered, defer-max) ----------------
// grid 512 flat (XCD-chunked remap), 256 thr = 4 waves; block handles q-tiles pr and 31-pr.
// Per wave: 16 q rows; lane owns q = lane&15. P in padded LDS (stride 72 u16 -> bank-uniform).

__global__ __launch_bounds__(256, 2) void flash_kernel(
    const u16* __restrict__ qg,   // [B][16][S][64]
    const u16* __restrict__ kg,   // [B][4][S][64]
    const u16* __restrict__ vtg,  // [B][4][64][S]
    u16* __restrict__ og) {       // [B][S][1024]
  const int tid = threadIdx.x, lane = tid & 63, w = tid >> 6;
  const int g = lane >> 4, l15 = lane & 15;

  // XCD-chunked remap: 64 consecutive logical blocks (one kvh group) per XCD
  const int bid = blockIdx.x;
  const int lid = (bid & 7) * 64 + (bid >> 3);
  const int pr = lid & 15, h = (lid >> 4) & 15, b = lid >> 8;
  const int kvh = h >> 2;

  __shared__ __align__(16) u16 Kl[2][64 * 64];   // [kv][d], 16B-XOR swizzled
  __shared__ __align__(16) u16 Vl[2][64 * 64];   // [d][kv], 16B-XOR swizzled
  __shared__ __align__(16) u16 Pl[4][16][72];    // per-wave P^T [q][kv], +8 pad (no conflicts)

  const u16* Kp = kg  + ((long)(b * 4 + kvh)) * 2048 * 64;
  const u16* Vp = vtg + ((long)(b * 4 + kvh)) * 64 * 2048;

  auto STAGE = [&](int buf, int kt) {
#pragma unroll
    for (int j = 0; j < 2; ++j) {
      const int lbase = j * 256 + w * 64;          // wave-uniform chunk base
      const int c = lbase + lane;
      const int row = c >> 3, c8 = c & 7;
      const int cs = (c8 ^ (row & 7)) * 8;         // inverse-swizzled source (rule #21)
      g2l16(Kp + ((long)(kt * 64 + row)) * 64 + cs, (char*)Kl[buf] + lbase * 16);
      g2l16(Vp + (long)row * 2048 + kt * 64 + cs,  (char*)Vl[buf] + lbase * 16);
    }
  };

#pragma unroll 1
  for (int pass = 0; pass < 2; ++pass) {
    const int qt = pass ? (31 - pr) : pr;
    const u16* Qp = qg + (((long)(b * 16 + h)) * 2048 + qt * 64 + w * 16) * 64;
    const s16x8 qf0 = *(const s16x8*)(Qp + l15 * 64 + g * 8);
    const s16x8 qf1 = *(const s16x8*)(Qp + l15 * 64 + 32 + g * 8);

    f32x4 of[4] = {};
    float m = -1e30f, lsum = 0.f;
    const int qrow = qt * 64 + w * 16 + l15;

    int cur = 0;
    STAGE(0, 0);

#pragma unroll 1
    for (int kt = 0; kt <= qt; ++kt) {
      if (kt < qt) {
        STAGE(cur ^ 1, kt + 1);
        asm volatile("s_waitcnt vmcnt(4)" ::: "memory");   // cur's 4 loads done; next 4 in flight
      } else {
        asm volatile("s_waitcnt vmcnt(0)" ::: "memory");
      }
      __builtin_amdgcn_s_barrier();
      const u16* Kb = Kl[cur];
      const u16* Vb = Vl[cur];

      // S^T tile: mfma(K, Q) -> C[kv][q], lane owns q = l15, 16 kv values in regs
      f32x4 sf[4] = {};
      __builtin_amdgcn_s_setprio(1);
#pragma unroll
      for (int ks = 0; ks < 2; ++ks) {
        const s16x8 qv = ks ? qf1 : qf0;
#pragma unroll
        for (int fn = 0; fn < 4; ++fn) {
          const int row = fn * 16 + l15;
          const s16x8 kf = *(const s16x8*)((const char*)Kb + row * 128 + (((ks * 4 + g) ^ (row & 7)) << 4));
          sf[fn] = __builtin_amdgcn_mfma_f32_16x16x32_bf16(kf, qv, sf[fn], 0, 0, 0);
        }
      }
      __builtin_amdgcn_s_setprio(0);

      // causal mask; row max via max3-friendly triples (+2 shuffles)
      const bool diag = (kt == qt);
      float p[16];
#pragma unroll
      for (int fn = 0; fn < 4; ++fn)
#pragma unroll
        for (int r = 0; r < 4; ++r) {
          float sv = sf[fn][r];
          if (diag) {
            const int kv = kt * 64 + fn * 16 + 4 * g + r;
            if (kv > qrow) sv = -1e30f;
          }
          p[fn * 4 + r] = sv;
        }
      const float t0 = fmaxf(fmaxf(p[0], p[1]), p[2]);
      const float t1 = fmaxf(fmaxf(p[3], p[4]), p[5]);
      const float t2 = fmaxf(fmaxf(p[6], p[7]), p[8]);
      const float t3 = fmaxf(fmaxf(p[9], p[10]), p[11]);
      const float t4 = fmaxf(fmaxf(p[12], p[13]), p[14]);
      float mx = fmaxf(fmaxf(fmaxf(t0, t1), t2), fmaxf(fmaxf(t3, t4), p[15]));
      mx = fmaxf(mx, __shfl_xor(mx, 16));
      mx = fmaxf(mx, __shfl_xor(mx, 32));

      // defer-max (T13): rescale only when max grew by > 11 (base-2)
      if (!__all(mx - m <= 11.0f)) {
        const float mn = fmaxf(m, mx);
        const float al = exp2fast(m - mn);
        m = mn;
        lsum *= al;
        float alq[4];
#pragma unroll
        for (int r = 0; r < 4; ++r) alq[r] = __shfl(al, 4 * g + r);
#pragma unroll
        for (int fd = 0; fd < 4; ++fd)
#pragma unroll
          for (int r = 0; r < 4; ++r) of[fd][r] *= alq[r];
      }

#pragma unroll
      for (int i = 0; i < 16; ++i) p[i] = exp2fast(p[i] - m);
      const float s0 = (p[0] + p[1]) + (p[2] + p[3]);
      const float s1 = (p[4] + p[5]) + (p[6] + p[7]);
      const float s2 = (p[8] + p[9]) + (p[10] + p[11]);
      const float s3 = (p[12] + p[13]) + (p[14] + p[15]);
      float rs = (s0 + s1) + (s2 + s3);
      rs += __shfl_xor(rs, 16);
      rs += __shfl_xor(rs, 32);
      lsum += rs;

      // P^T -> padded LDS [q][kv] via v_cvt_pk_bf16_f32 (4 b64 writes, bank-uniform)
      u16* Pw = &Pl[w][l15][0];
#pragma unroll
      for (int fn = 0; fn < 4; ++fn) {
        const u32x2 v2 = {cvt_pk(p[fn * 4 + 0], p[fn * 4 + 1]),
                          cvt_pk(p[fn * 4 + 2], p[fn * 4 + 3])};
        *(u32x2*)(Pw + fn * 16 + g * 4) = v2;    // kv = fn*16 + 4g
      }

      // O += P @ V : A-frag = P rows (q), B-frag = V^T rows (d)
      __builtin_amdgcn_s_setprio(1);
#pragma unroll
      for (int ks = 0; ks < 2; ++ks) {
        const s16x8 pa = *(const s16x8*)(&Pl[w][l15][ks * 32 + g * 8]);
#pragma unroll
        for (int fd = 0; fd < 4; ++fd) {
          const int vrow = fd * 16 + l15;
          const s16x8 vf = *(const s16x8*)((const char*)Vb + vrow * 128 + (((ks * 4 + g) ^ (vrow & 7)) << 4));
          of[fd] = __builtin_amdgcn_mfma_f32_16x16x32_bf16(pa, vf, of[fd], 0, 0, 0);
        }
      }
      __builtin_amdgcn_s_setprio(0);

      __builtin_amdgcn_s_barrier();   // all waves done reading cur before it's restaged
      cur ^= 1;
    }

    // normalize + store; of rows are q_local = 4g+r, stats live at lane 4g+r
    float linv[4];
#pragma unroll
    for (int r = 0; r < 4; ++r) linv[r] = 1.0f / __shfl(lsum, 4 * g + r);
    const long orow0 = (long)b * 2048 + qt * 64 + w * 16 + 4 * g;
#pragma unroll
    for (int r = 0; r < 4; ++r) {
      const long gb = (orow0 + r) * 1024 + h * 64;
#pragma unroll
      for (int fd = 0; fd < 4; ++fd)
        og[gb + fd * 16 + l15] = f2bf(of[fd][r] * linv[r]);
    }
  }
}

// ---------------- launch ----------------

extern "C" void kernel_launch(void* const* d_in, const int* in_sizes, int n_in,
                              void* d_out, int out_size, void* d_ws, size_t ws_size,
                              hipStream_t stream) {
  (void)in_sizes; (void)n_in; (void)out_size; (void)ws_size;
  const float* x  = (const float*)d_in[0];
  const float* wq = (const float*)d_in[1];
  const float* wk = (const float*)d_in[2];
  const float* wv = (const float*)d_in[3];
  const float* wo = (const float*)d_in[4];
  float* out = (float*)d_out;

  char* p = (char*)d_ws;
  auto alloc = [&](size_t bytes) { char* r = p; p += (bytes + 255) & ~(size_t)255; return r; };

  u16* xb    = (u16*)alloc(4096ull * 1024 * 2);
  u16* wcat  = (u16*)alloc(1536ull * 1024 * 2);   // [wq; wk; wv]
  u16* wob   = (u16*)alloc(1024ull * 1024 * 2);
  u16* qrb   = (u16*)alloc(4096ull * 1024 * 2);   // [B][16][S][64]
  u16* krb   = (u16*)alloc(4096ull * 256 * 2);    // [B][4][S][64]
  u16* vtb   = (u16*)alloc(4096ull * 256 * 2);    // [B][4][64][S]
  u16* aob   = (u16*)alloc(4096ull * 1024 * 2);   // [B][S][1024]
  float* cosT = (float*)alloc(2048ull * 32 * 4);
  float* sinT = (float*)alloc(2048ull * 32 * 4);

  // single fused prep: weight/x conversions + trig tables
  prep_kernel<<<6720, 256, 0, stream>>>(x, wq, wk, wv, wo, xb, wcat, wob, cosT, sinT);

  // fused QKV projection + rope + layout
  gemm_qkv_kernel<<<dim3(32, 12), 256, 0, stream>>>(xb, wcat, qrb, krb, vtb, cosT, sinT);

  // causal GQA flash attention
  flash_kernel<<<512, 256, 0, stream>>>(qrb, krb, vtb, aob);

  // output projection (fp32 out)
  gemm_out_kernel<<<dim3(32, 8), 256, 0, stream>>>(aob, wob, out);
}

// Round 7
// 168.184 us; speedup vs baseline: 2.1000x; 1.0385x over previous
//
#include <hip/hip_runtime.h>
#include <stdint.h>

typedef unsigned short u16;
typedef __attribute__((ext_vector_type(8))) short s16x8;   // bf16x8 MFMA frag (4 VGPRs)
typedef __attribute__((ext_vector_type(4))) float f32x4;   // MFMA C/D frag
typedef __attribute__((ext_vector_type(4))) unsigned short u16x4;
typedef __attribute__((ext_vector_type(2))) unsigned int u32x2;

// ---------------- helpers ----------------

__device__ __forceinline__ u16 f2bf(float f) {
  unsigned u = __float_as_uint(f);
  unsigned r = (u + 0x7fffu + ((u >> 16) & 1u)) >> 16;   // RNE
  return (u16)r;
}
__device__ __forceinline__ unsigned cvt_pk(float lo, float hi) {
  unsigned r;
  asm("v_cvt_pk_bf16_f32 %0, %1, %2" : "=v"(r) : "v"(lo), "v"(hi));
  return r;
}
__device__ __forceinline__ float exp2fast(float x) {
  return __builtin_amdgcn_exp2f(x);   // v_exp_f32: D = 2^S0
}

typedef const __attribute__((address_space(1))) unsigned int* gas_ptr;
typedef __attribute__((address_space(3))) unsigned int* las_ptr;

__device__ __forceinline__ void g2l16(const void* g, void* l) {
  __builtin_amdgcn_global_load_lds((gas_ptr)g, (las_ptr)l, 16, 0, 0);
}

__device__ __forceinline__ void cvt4(const float* __restrict__ in, u16* __restrict__ out) {
  const f32x4 v = *(const f32x4*)in;
  u16x4 o;
  o[0] = f2bf(v[0]); o[1] = f2bf(v[1]); o[2] = f2bf(v[2]); o[3] = f2bf(v[3]);
  *(u16x4*)out = o;
}

// ---------------- fused prep: all bf16 conversions + trig tables ----------------

__global__ void prep_kernel(const float* __restrict__ x,  const float* __restrict__ wq,
                            const float* __restrict__ wk, const float* __restrict__ wv,
                            const float* __restrict__ wo,
                            u16* __restrict__ xb, u16* __restrict__ wcat, u16* __restrict__ wob,
                            float* __restrict__ cosT, float* __restrict__ sinT) {
  const long id = (long)blockIdx.x * 256 + threadIdx.x;
  if (id < 262144) {                       // wq -> wcat rows 0..1023
    cvt4(wq + id * 4, wcat + id * 4);
  } else if (id < 327680) {                // wk -> wcat rows 1024..1279
    const long i = id - 262144;
    cvt4(wk + i * 4, wcat + 1048576 + i * 4);
  } else if (id < 393216) {                // wv -> wcat rows 1280..1535
    const long i = id - 327680;
    cvt4(wv + i * 4, wcat + 1310720 + i * 4);
  } else if (id < 655360) {                // wo
    const long i = id - 393216;
    cvt4(wo + i * 4, wob + i * 4);
  } else if (id < 671744) {                // trig tables, 4 entries per id
    const long t = id - 655360;
#pragma unroll
    for (int u = 0; u < 4; ++u) {
      const long idx = t * 4 + u;
      const int s = (int)(idx >> 5), j = (int)(idx & 31);
      const double invd = exp(-(double)j * 0.2878231366242558);  // ln(10000)/32
      const float a = (float)s * (float)invd;
      cosT[idx] = cosf(a);
      sinT[idx] = sinf(a);
    }
  } else {                                 // x
    const long i = id - 671744;
    cvt4(x + i * 4, xb + i * 4);
  }
}

// ---------------- fused QKV projection GEMM (BK=64, dbuf, swizzled LDS) ----------------
// Y[4096,1536] = X @ Wcat^T; epilogue: RoPE, Q scaled by 0.125*log2(e), writes
//   Q  -> [B][16][S][64] bf16, K -> [B][4][S][64] bf16, V^T -> [B][4][64][S] bf16
// V blocks (blockIdx.y >= 10) run the K-loop with swapped MFMA operands so the
// C fragment comes out transposed (rows = d, cols = s) -> coalesced V^T store.

__global__ __launch_bounds__(256, 2) void gemm_qkv_kernel(
    const u16* __restrict__ A, const u16* __restrict__ W,
    u16* __restrict__ qo, u16* __restrict__ ko, u16* __restrict__ vto,
    const float* __restrict__ cosT, const float* __restrict__ sinT) {
  const int K = 1024;
  __shared__ __align__(16) u16 As[2][128 * 64];
  __shared__ __align__(16) u16 Bs[2][128 * 64];
  const int tid = threadIdx.x;
  const int lane = tid & 63;
  const int wave = tid >> 6;
  const int g = lane >> 4, l15 = lane & 15;
  const int wr = wave >> 1, wc = wave & 1;
  const long arow0 = (long)blockIdx.x * 128;
  const long wrow0 = (long)blockIdx.y * 128;
  const u16* Ab = A + arow0 * K;
  const u16* Wb = W + wrow0 * K;
  const bool isV = (blockIdx.y >= 10);

  auto STAGE = [&](int buf, int k0) {
#pragma unroll
    for (int i = 0; i < 4; ++i) {
      const int lbase = i * 256 + wave * 64;
      const int c = lbase + lane;
      const int r = c >> 3, c8 = c & 7;
      const int cs = (c8 ^ (r & 7)) * 8;       // inverse-swizzled source (rule #21)
      g2l16(Ab + (long)r * K + k0 + cs, (char*)As[buf] + lbase * 16);
      g2l16(Wb + (long)r * K + k0 + cs, (char*)Bs[buf] + lbase * 16);
    }
  };

  f32x4 acc[4][4] = {};
  int cur = 0;
  STAGE(0, 0);

  for (int k0 = 0; k0 < K; k0 += 64) {
    if (k0 + 64 < K) {
      STAGE(cur ^ 1, k0 + 64);
      asm volatile("s_waitcnt vmcnt(8)" ::: "memory");   // cur's 8 loads done; next 8 in flight
    } else {
      asm volatile("s_waitcnt vmcnt(0)" ::: "memory");
    }
    __builtin_amdgcn_s_barrier();
#pragma unroll
    for (int ks = 0; ks < 2; ++ks) {
      s16x8 af[4], bfr[4];
#pragma unroll
      for (int m = 0; m < 4; ++m) {
        const int row = wr * 64 + m * 16 + l15;
        af[m] = *(const s16x8*)((const char*)As[cur] + row * 128 + (((ks * 4 + g) ^ (row & 7)) << 4));
      }
#pragma unroll
      for (int n = 0; n < 4; ++n) {
        const int row = wc * 64 + n * 16 + l15;
        bfr[n] = *(const s16x8*)((const char*)Bs[cur] + row * 128 + (((ks * 4 + g) ^ (row & 7)) << 4));
      }
      __builtin_amdgcn_s_setprio(1);
      if (!isV) {
#pragma unroll
        for (int m = 0; m < 4; ++m)
#pragma unroll
          for (int n = 0; n < 4; ++n)
            acc[m][n] = __builtin_amdgcn_mfma_f32_16x16x32_bf16(af[m], bfr[n], acc[m][n], 0, 0, 0);
      } else {
        // swapped: acc[mw][nx], rows = W-dim (d), cols = X-dim (s)
#pragma unroll
        for (int m = 0; m < 4; ++m)
#pragma unroll
          for (int n = 0; n < 4; ++n)
            acc[m][n] = __builtin_amdgcn_mfma_f32_16x16x32_bf16(bfr[m], af[n], acc[m][n], 0, 0, 0);
      }
      __builtin_amdgcn_s_setprio(0);
    }
    __builtin_amdgcn_s_barrier();
    cur ^= 1;
  }

  const int colBase = (int)wrow0 + wc * 64;
  const int j0 = l15;
  const float QSCALE = 0.18033688011112042f;   // 0.125 * log2(e): softmax done in base 2

  if (colBase < 1024) {                       // ---- Q: rope + scale ----
    const int h2 = colBase >> 6;
#pragma unroll
    for (int m = 0; m < 4; ++m) {
      const int grow = (int)arow0 + wr * 64 + m * 16 + g * 4;
#pragma unroll
      for (int r = 0; r < 4; ++r) {
        const int row = grow + r;
        const int s = row & 2047, bb = row >> 11;
        const long ob = (((long)(bb * 16 + h2)) * 2048 + s) * 64;
        const float c0 = cosT[s * 32 + j0],      s0 = sinT[s * 32 + j0];
        const float c1 = cosT[s * 32 + 16 + j0], s1 = sinT[s * 32 + 16 + j0];
        qo[ob + j0]      = f2bf((acc[m][0][r] * c0 - acc[m][2][r] * s0) * QSCALE);
        qo[ob + 16 + j0] = f2bf((acc[m][1][r] * c1 - acc[m][3][r] * s1) * QSCALE);
        qo[ob + 32 + j0] = f2bf((acc[m][2][r] * c0 + acc[m][0][r] * s0) * QSCALE);
        qo[ob + 48 + j0] = f2bf((acc[m][3][r] * c1 + acc[m][1][r] * s1) * QSCALE);
      }
    }
  } else if (colBase < 1280) {                // ---- K: rope ----
    const int kvh2 = (colBase - 1024) >> 6;
#pragma unroll
    for (int m = 0; m < 4; ++m) {
      const int grow = (int)arow0 + wr * 64 + m * 16 + g * 4;
#pragma unroll
      for (int r = 0; r < 4; ++r) {
        const int row = grow + r;
        const int s = row & 2047, bb = row >> 11;
        const long ob = (((long)(bb * 4 + kvh2)) * 2048 + s) * 64;
        const float c0 = cosT[s * 32 + j0],      s0 = sinT[s * 32 + j0];
        const float c1 = cosT[s * 32 + 16 + j0], s1 = sinT[s * 32 + 16 + j0];
        ko[ob + j0]      = f2bf(acc[m][0][r] * c0 - acc[m][2][r] * s0);
        ko[ob + 16 + j0] = f2bf(acc[m][1][r] * c1 - acc[m][3][r] * s1);
        ko[ob + 32 + j0] = f2bf(acc[m][2][r] * c0 + acc[m][0][r] * s0);
        ko[ob + 48 + j0] = f2bf(acc[m][3][r] * c1 + acc[m][1][r] * s1);
      }
    }
  } else {                                    // ---- V (swapped acc): coalesced V^T store ----
    const int kvh2 = (colBase - 1280) >> 6;
    const int bb = (int)(arow0 >> 11);
    const int sBase = (int)(arow0 & 2047) + wr * 64;
    const long vrow0 = ((long)(bb * 4 + kvh2)) * 64;
#pragma unroll
    for (int mw = 0; mw < 4; ++mw) {          // W 16-row group (d)
      const int d0 = mw * 16 + g * 4;
#pragma unroll
      for (int r = 0; r < 4; ++r) {
        const long db = (vrow0 + d0 + r) * 2048;
#pragma unroll
        for (int nx = 0; nx < 4; ++nx)        // X 16-row group (s)
          vto[db + sBase + nx * 16 + l15] = f2bf(acc[mw][nx][r]);
      }
    }
  }
}

// ---------------- output projection GEMM (BK=64, dbuf, swizzled, fp32 out) ----------------

__global__ __launch_bounds__(256, 2) void gemm_out_kernel(
    const u16* __restrict__ A, const u16* __restrict__ W, float* __restrict__ Y) {
  const int K = 1024, N = 1024;
  __shared__ __align__(16) u16 As[2][128 * 64];
  __shared__ __align__(16) u16 Bs[2][128 * 64];
  const int tid = threadIdx.x;
  const int lane = tid & 63;
  const int wave = tid >> 6;
  const int g = lane >> 4, l15 = lane & 15;
  const int wr = wave >> 1, wc = wave & 1;
  const long arow0 = (long)blockIdx.x * 128;
  const long wrow0 = (long)blockIdx.y * 128;
  const u16* Ab = A + arow0 * K;
  const u16* Wb = W + wrow0 * K;

  auto STAGE = [&](int buf, int k0) {
#pragma unroll
    for (int i = 0; i < 4; ++i) {
      const int lbase = i * 256 + wave * 64;
      const int c = lbase + lane;
      const int r = c >> 3, c8 = c & 7;
      const int cs = (c8 ^ (r & 7)) * 8;
      g2l16(Ab + (long)r * K + k0 + cs, (char*)As[buf] + lbase * 16);
      g2l16(Wb + (long)r * K + k0 + cs, (char*)Bs[buf] + lbase * 16);
    }
  };

  f32x4 acc[4][4] = {};
  int cur = 0;
  STAGE(0, 0);

  for (int k0 = 0; k0 < K; k0 += 64) {
    if (k0 + 64 < K) {
      STAGE(cur ^ 1, k0 + 64);
      asm volatile("s_waitcnt vmcnt(8)" ::: "memory");
    } else {
      asm volatile("s_waitcnt vmcnt(0)" ::: "memory");
    }
    __builtin_amdgcn_s_barrier();
#pragma unroll
    for (int ks = 0; ks < 2; ++ks) {
      s16x8 af[4], bfr[4];
#pragma unroll
      for (int m = 0; m < 4; ++m) {
        const int row = wr * 64 + m * 16 + l15;
        af[m] = *(const s16x8*)((const char*)As[cur] + row * 128 + (((ks * 4 + g) ^ (row & 7)) << 4));
      }
#pragma unroll
      for (int n = 0; n < 4; ++n) {
        const int row = wc * 64 + n * 16 + l15;
        bfr[n] = *(const s16x8*)((const char*)Bs[cur] + row * 128 + (((ks * 4 + g) ^ (row & 7)) << 4));
      }
      __builtin_amdgcn_s_setprio(1);
#pragma unroll
      for (int m = 0; m < 4; ++m)
#pragma unroll
        for (int n = 0; n < 4; ++n)
          acc[m][n] = __builtin_amdgcn_mfma_f32_16x16x32_bf16(af[m], bfr[n], acc[m][n], 0, 0, 0);
      __builtin_amdgcn_s_setprio(0);
    }
    __builtin_amdgcn_s_barrier();
    cur ^= 1;
  }

#pragma unroll
  for (int m = 0; m < 4; ++m)
#pragma unroll
    for (int n = 0; n < 4; ++n) {
      const long gr0 = arow0 + wr * 64 + m * 16 + g * 4;
      const long gc = wrow0 + wc * 64 + n * 16 + l15;
#pragma unroll
      for (int r = 0; r < 4; ++r)
        Y[(gr0 + r) * N + gc] = acc[m][n][r];
    }
}

// ---------------- flash attention (swapped QK^T, double-buffered, defer-max) ----------------
// grid 512 flat (XCD-chunked remap), 256 thr = 4 waves; block handles q-tiles pr and 31-pr.
// Per wave: 16 q rows; lane owns q = lane&15. P in padded LDS (stride 72 u16).

__global__ __launch_bounds__(256, 2) void flash_kernel(
    const u16* __restrict__ qg,   // [B][16][S][64]
    const u16* __restrict__ kg,   // [B][4][S][64]
    const u16* __restrict__ vtg,  // [B][4][64][S]
    u16* __restrict__ og) {       // [B][S][1024]
  const int tid = threadIdx.x, lane = tid & 63, w = tid >> 6;
  const int g = lane >> 4, l15 = lane & 15;

  // XCD-chunked remap: 64 consecutive logical blocks (one kvh group) per XCD
  const int bid = blockIdx.x;
  const int lid = (bid & 7) * 64 + (bid >> 3);
  const int pr = lid & 15, h = (lid >> 4) & 15, b = lid >> 8;
  const int kvh = h >> 2;

  __shared__ __align__(16) u16 Kl[2][64 * 64];   // [kv][d], 16B-XOR swizzled
  __shared__ __align__(16) u16 Vl[2][64 * 64];   // [d][kv], 16B-XOR swizzled
  __shared__ __align__(16) u16 Pl[4][16][72];    // per-wave P^T [q][kv], +8 pad

  const u16* Kp = kg  + ((long)(b * 4 + kvh)) * 2048 * 64;
  const u16* Vp = vtg + ((long)(b * 4 + kvh)) * 64 * 2048;

  auto STAGE = [&](int buf, int kt) {
#pragma unroll
    for (int j = 0; j < 2; ++j) {
      const int lbase = j * 256 + w * 64;          // wave-uniform chunk base
      const int c = lbase + lane;
      const int row = c >> 3, c8 = c & 7;
      const int cs = (c8 ^ (row & 7)) * 8;         // inverse-swizzled source (rule #21)
      g2l16(Kp + ((long)(kt * 64 + row)) * 64 + cs, (char*)Kl[buf] + lbase * 16);
      g2l16(Vp + (long)row * 2048 + kt * 64 + cs,  (char*)Vl[buf] + lbase * 16);
    }
  };

#pragma unroll 1
  for (int pass = 0; pass < 2; ++pass) {
    const int qt = pass ? (31 - pr) : pr;
    const u16* Qp = qg + (((long)(b * 16 + h)) * 2048 + qt * 64 + w * 16) * 64;
    const s16x8 qf0 = *(const s16x8*)(Qp + l15 * 64 + g * 8);
    const s16x8 qf1 = *(const s16x8*)(Qp + l15 * 64 + 32 + g * 8);

    f32x4 of[4] = {};
    float m = -1e30f, lsum = 0.f;
    const int qrow = qt * 64 + w * 16 + l15;

    int cur = 0;
    STAGE(0, 0);

#pragma unroll 1
    for (int kt = 0; kt <= qt; ++kt) {
      if (kt < qt) {
        STAGE(cur ^ 1, kt + 1);
        asm volatile("s_waitcnt vmcnt(4)" ::: "memory");   // cur's 4 loads done; next 4 in flight
      } else {
        asm volatile("s_waitcnt vmcnt(0)" ::: "memory");
      }
      __builtin_amdgcn_s_barrier();
      const u16* Kb = Kl[cur];
      const u16* Vb = Vl[cur];

      // S^T tile: mfma(K, Q) -> C[kv][q], lane owns q = l15, 16 kv values in regs
      f32x4 sf[4] = {};
      __builtin_amdgcn_s_setprio(1);
#pragma unroll
      for (int ks = 0; ks < 2; ++ks) {
        const s16x8 qv = ks ? qf1 : qf0;
#pragma unroll
        for (int fn = 0; fn < 4; ++fn) {
          const int row = fn * 16 + l15;
          const s16x8 kf = *(const s16x8*)((const char*)Kb + row * 128 + (((ks * 4 + g) ^ (row & 7)) << 4));
          sf[fn] = __builtin_amdgcn_mfma_f32_16x16x32_bf16(kf, qv, sf[fn], 0, 0, 0);
        }
      }
      __builtin_amdgcn_s_setprio(0);

      // causal mask; row max via max3-friendly triples (+2 shuffles)
      const bool diag = (kt == qt);
      float p[16];
#pragma unroll
      for (int fn = 0; fn < 4; ++fn)
#pragma unroll
        for (int r = 0; r < 4; ++r) {
          float sv = sf[fn][r];
          if (diag) {
            const int kv = kt * 64 + fn * 16 + 4 * g + r;
            if (kv > qrow) sv = -1e30f;
          }
          p[fn * 4 + r] = sv;
        }
      const float t0 = fmaxf(fmaxf(p[0], p[1]), p[2]);
      const float t1 = fmaxf(fmaxf(p[3], p[4]), p[5]);
      const float t2 = fmaxf(fmaxf(p[6], p[7]), p[8]);
      const float t3 = fmaxf(fmaxf(p[9], p[10]), p[11]);
      const float t4 = fmaxf(fmaxf(p[12], p[13]), p[14]);
      float mx = fmaxf(fmaxf(fmaxf(t0, t1), t2), fmaxf(fmaxf(t3, t4), p[15]));
      mx = fmaxf(mx, __shfl_xor(mx, 16));
      mx = fmaxf(mx, __shfl_xor(mx, 32));

      // defer-max (T13): rescale only when max grew by > 11 (base-2)
      if (!__all(mx - m <= 11.0f)) {
        const float mn = fmaxf(m, mx);
        const float al = exp2fast(m - mn);
        m = mn;
        lsum *= al;
        float alq[4];
#pragma unroll
        for (int r = 0; r < 4; ++r) alq[r] = __shfl(al, 4 * g + r);
#pragma unroll
        for (int fd = 0; fd < 4; ++fd)
#pragma unroll
          for (int r = 0; r < 4; ++r) of[fd][r] *= alq[r];
      }

#pragma unroll
      for (int i = 0; i < 16; ++i) p[i] = exp2fast(p[i] - m);
      const float s0 = (p[0] + p[1]) + (p[2] + p[3]);
      const float s1 = (p[4] + p[5]) + (p[6] + p[7]);
      const float s2 = (p[8] + p[9]) + (p[10] + p[11]);
      const float s3 = (p[12] + p[13]) + (p[14] + p[15]);
      float rs = (s0 + s1) + (s2 + s3);
      rs += __shfl_xor(rs, 16);
      rs += __shfl_xor(rs, 32);
      lsum += rs;

      // P^T -> padded LDS [q][kv] via v_cvt_pk_bf16_f32 (4 b64 writes)
      u16* Pw = &Pl[w][l15][0];
#pragma unroll
      for (int fn = 0; fn < 4; ++fn) {
        const u32x2 v2 = {cvt_pk(p[fn * 4 + 0], p[fn * 4 + 1]),
                          cvt_pk(p[fn * 4 + 2], p[fn * 4 + 3])};
        *(u32x2*)(Pw + fn * 16 + g * 4) = v2;    // kv = fn*16 + 4g
      }

      // O += P @ V : A-frag = P rows (q), B-frag = V^T rows (d)
      __builtin_amdgcn_s_setprio(1);
#pragma unroll
      for (int ks = 0; ks < 2; ++ks) {
        const s16x8 pa = *(const s16x8*)(&Pl[w][l15][ks * 32 + g * 8]);
#pragma unroll
        for (int fd = 0; fd < 4; ++fd) {
          const int vrow = fd * 16 + l15;
          const s16x8 vf = *(const s16x8*)((const char*)Vb + vrow * 128 + (((ks * 4 + g) ^ (vrow & 7)) << 4));
          of[fd] = __builtin_amdgcn_mfma_f32_16x16x32_bf16(pa, vf, of[fd], 0, 0, 0);
        }
      }
      __builtin_amdgcn_s_setprio(0);

      __builtin_amdgcn_s_barrier();   // all waves done reading cur before it's restaged
      cur ^= 1;
    }

    // normalize + store; of rows are q_local = 4g+r, stats live at lane 4g+r
    float linv[4];
#pragma unroll
    for (int r = 0; r < 4; ++r) linv[r] = 1.0f / __shfl(lsum, 4 * g + r);
    const long orow0 = (long)b * 2048 + qt * 64 + w * 16 + 4 * g;
#pragma unroll
    for (int r = 0; r < 4; ++r) {
      const long gb = (orow0 + r) * 1024 + h * 64;
#pragma unroll
      for (int fd = 0; fd < 4; ++fd)
        og[gb + fd * 16 + l15] = f2bf(of[fd][r] * linv[r]);
    }
  }
}

// ---------------- launch ----------------

extern "C" void kernel_launch(void* const* d_in, const int* in_sizes, int n_in,
                              void* d_out, int out_size, void* d_ws, size_t ws_size,
                              hipStream_t stream) {
  (void)in_sizes; (void)n_in; (void)out_size; (void)ws_size;
  const float* x  = (const float*)d_in[0];
  const float* wq = (const float*)d_in[1];
  const float* wk = (const float*)d_in[2];
  const float* wv = (const float*)d_in[3];
  const float* wo = (const float*)d_in[4];
  float* out = (float*)d_out;

  char* p = (char*)d_ws;
  auto alloc = [&](size_t bytes) { char* r = p; p += (bytes + 255) & ~(size_t)255; return r; };

  u16* xb    = (u16*)alloc(4096ull * 1024 * 2);
  u16* wcat  = (u16*)alloc(1536ull * 1024 * 2);   // [wq; wk; wv]
  u16* wob   = (u16*)alloc(1024ull * 1024 * 2);
  u16* qrb   = (u16*)alloc(4096ull * 1024 * 2);   // [B][16][S][64]
  u16* krb   = (u16*)alloc(4096ull * 256 * 2);    // [B][4][S][64]
  u16* vtb   = (u16*)alloc(4096ull * 256 * 2);    // [B][4][64][S]
  u16* aob   = (u16*)alloc(4096ull * 1024 * 2);   // [B][S][1024]
  float* cosT = (float*)alloc(2048ull * 32 * 4);
  float* sinT = (float*)alloc(2048ull * 32 * 4);

  // single fused prep: weight/x conversions + trig tables
  prep_kernel<<<6720, 256, 0, stream>>>(x, wq, wk, wv, wo, xb, wcat, wob, cosT, sinT);

  // fused QKV projection + rope + layout
  gemm_qkv_kernel<<<dim3(32, 12), 256, 0, stream>>>(xb, wcat, qrb, krb, vtb, cosT, sinT);

  // causal GQA flash attention
  flash_kernel<<<512, 256, 0, stream>>>(qrb, krb, vtb, aob);

  // output projection (fp32 out)
  gemm_out_kernel<<<dim3(32, 8), 256, 0, stream>>>(aob, wob, out);
}